// Round 2
// baseline (223.019 us; speedup 1.0000x reference)
//
#include <hip/hip_runtime.h>
#include <hip/hip_bf16.h>

typedef __hip_bfloat16 bf16;
typedef short v8s __attribute__((ext_vector_type(8)));
typedef float v4f __attribute__((ext_vector_type(4)));

#define S_ 2048
#define D_ 1024
#define H_ 16
#define HD_ 64

#define EXP2F(x) __builtin_amdgcn_exp2f(x)   /* v_exp_f32: 2^x on gfx950 */
#define NEG_BIG (-1.0e30f)
#define C2 0.1803368801111244f   /* (1/sqrt(64)) * log2(e), folded into Q */

#define GLDS16(g, l) __builtin_amdgcn_global_load_lds(                        \
    (const __attribute__((address_space(1))) unsigned int*)(g),               \
    (__attribute__((address_space(3))) unsigned int*)(l), 16, 0, 0)

#define CVT_PK(d, lo, hi) \
    asm("v_cvt_pk_bf16_f32 %0, %1, %2" : "=v"(d) : "v"(lo), "v"(hi))

static __device__ __forceinline__ unsigned short bf16_bits(bf16 h) {
    union { bf16 h; unsigned short u; } c; c.h = h; return c.u;
}

static __device__ __forceinline__ v8s pack_bf16x8(const float4 a, const float4 b) {
    union { v8s v; unsigned short u[8]; } r;
    r.u[0] = bf16_bits(__float2bfloat16(a.x));
    r.u[1] = bf16_bits(__float2bfloat16(a.y));
    r.u[2] = bf16_bits(__float2bfloat16(a.z));
    r.u[3] = bf16_bits(__float2bfloat16(a.w));
    r.u[4] = bf16_bits(__float2bfloat16(b.x));
    r.u[5] = bf16_bits(__float2bfloat16(b.y));
    r.u[6] = bf16_bits(__float2bfloat16(b.z));
    r.u[7] = bf16_bits(__float2bfloat16(b.w));
    return r.v;
}

// ---------------------------------------------------------------------------
// fp32 -> bf16 conversion pre-pass
// ---------------------------------------------------------------------------
__global__ __launch_bounds__(256)
void cvt_bf16(const float* __restrict__ x,  const float* __restrict__ wq,
              const float* __restrict__ wk, const float* __restrict__ wv,
              const float* __restrict__ wo,
              bf16* __restrict__ xb,  bf16* __restrict__ wqb,
              bf16* __restrict__ wkb, bf16* __restrict__ wvb,
              bf16* __restrict__ wob)
{
    const int seg = blockIdx.y;
    const float* src; bf16* dst; int n;
    switch (seg) {
        case 0: src = x;  dst = xb;  n = 4096 * 1024; break;
        case 1: src = wq; dst = wqb; n = 1024 * 1024; break;
        case 2: src = wk; dst = wkb; n = 1024 * 1024; break;
        case 3: src = wv; dst = wvb; n = 1024 * 1024; break;
        default:src = wo; dst = wob; n = 1024 * 1024; break;
    }
    const int idx = (blockIdx.x * 256 + threadIdx.x) * 8;
    if (idx >= n) return;
    *(v8s*)&dst[idx] = pack_bf16x8(*(const float4*)&src[idx],
                                   *(const float4*)&src[idx + 4]);
}

// ---------------------------------------------------------------------------
// FAST NT GEMM (m97-style): bf16 inputs, global_load_lds width-16 staging.
// ---------------------------------------------------------------------------
__global__ __launch_bounds__(256)
void gemm_qkv_f(const bf16* __restrict__ xb, const bf16* __restrict__ wqb,
                const bf16* __restrict__ wkb, const bf16* __restrict__ wvb,
                bf16* __restrict__ qd, bf16* __restrict__ kd, bf16* __restrict__ vtd)
{
    const int mode = blockIdx.z;
    const bf16* __restrict__ W = (mode == 0) ? wqb : (mode == 1) ? wkb : wvb;
    const int m0 = blockIdx.x * 128;
    const int n0 = blockIdx.y * 128;
    __shared__ bf16 As[128 * 32];
    __shared__ bf16 Bs[128 * 32];
    const int t    = threadIdx.x;
    const int lane = t & 63, w = t >> 6;
    const int wr = w >> 1, wc = w & 1;
    const int l15 = lane & 15, quad = lane >> 4;
    const int r16 = lane >> 2, c8 = (lane & 3) * 8;
    v4f acc[4][4] = {};

    const bf16* ga = &xb[(m0 + w*16 + r16) * 1024 + c8];
    const bf16* gb = &W [(n0 + w*16 + r16) * 1024 + c8];
    bf16* la0 = &As[w * 16 * 32];
    bf16* la1 = &As[(64 + w * 16) * 32];
    bf16* lb0 = &Bs[w * 16 * 32];
    bf16* lb1 = &Bs[(64 + w * 16) * 32];

    for (int k0 = 0; k0 < 1024; k0 += 32) {
        __syncthreads();
        GLDS16(ga + k0,             la0);
        GLDS16(ga + k0 + 64 * 1024, la1);
        GLDS16(gb + k0,             lb0);
        GLDS16(gb + k0 + 64 * 1024, lb1);
        __syncthreads();
        v8s a[4], b[4];
#pragma unroll
        for (int mt = 0; mt < 4; mt++) a[mt] = *(const v8s*)&As[(wr*64 + mt*16 + l15)*32 + quad*8];
#pragma unroll
        for (int nt = 0; nt < 4; nt++) b[nt] = *(const v8s*)&Bs[(wc*64 + nt*16 + l15)*32 + quad*8];
#pragma unroll
        for (int mt = 0; mt < 4; mt++)
#pragma unroll
            for (int nt = 0; nt < 4; nt++)
                acc[mt][nt] = __builtin_amdgcn_mfma_f32_16x16x32_bf16(a[mt], b[nt], acc[mt][nt], 0, 0, 0);
    }

    const float qscale = (mode == 0) ? C2 : 1.0f;
#pragma unroll
    for (int mt = 0; mt < 4; mt++) {
        const int mb = m0 + wr*64 + mt*16 + quad*4;
        const int b_ = mb >> 11, s = mb & 2047;
#pragma unroll
        for (int nt = 0; nt < 4; nt++) {
            const int n = n0 + wc*64 + nt*16 + l15;
            const int h = n >> 6, d = n & 63;
            if (mode == 2) {
                unsigned int lo = (unsigned int)bf16_bits(__float2bfloat16(acc[mt][nt][0]))
                                | ((unsigned int)bf16_bits(__float2bfloat16(acc[mt][nt][1])) << 16);
                unsigned int hi = (unsigned int)bf16_bits(__float2bfloat16(acc[mt][nt][2]))
                                | ((unsigned int)bf16_bits(__float2bfloat16(acc[mt][nt][3])) << 16);
                uint2 pv; pv.x = lo; pv.y = hi;
                *(uint2*)&vtd[((b_*H_ + h)*HD_ + d)*S_ + s] = pv;
            } else {
                bf16* __restrict__ dst = (mode == 0) ? qd : kd;
#pragma unroll
                for (int r = 0; r < 4; r++)
                    dst[((b_*H_ + h)*S_ + (s + r))*HD_ + d] = __float2bfloat16(acc[mt][nt][r] * qscale);
            }
        }
    }
}

__global__ __launch_bounds__(256)
void gemm_out_f(const bf16* __restrict__ ctx, const bf16* __restrict__ wob,
                const float* __restrict__ bo, float* __restrict__ out)
{
    const int m0 = blockIdx.x * 128;
    const int n0 = blockIdx.y * 128;
    __shared__ bf16 As[128 * 32];
    __shared__ bf16 Bs[128 * 32];
    const int t    = threadIdx.x;
    const int lane = t & 63, w = t >> 6;
    const int wr = w >> 1, wc = w & 1;
    const int l15 = lane & 15, quad = lane >> 4;
    const int r16 = lane >> 2, c8 = (lane & 3) * 8;
    v4f acc[4][4] = {};

    const bf16* ga = &ctx[(m0 + w*16 + r16) * 1024 + c8];
    const bf16* gb = &wob[(n0 + w*16 + r16) * 1024 + c8];
    bf16* la0 = &As[w * 16 * 32];
    bf16* la1 = &As[(64 + w * 16) * 32];
    bf16* lb0 = &Bs[w * 16 * 32];
    bf16* lb1 = &Bs[(64 + w * 16) * 32];

    for (int k0 = 0; k0 < 1024; k0 += 32) {
        __syncthreads();
        GLDS16(ga + k0,             la0);
        GLDS16(ga + k0 + 64 * 1024, la1);
        GLDS16(gb + k0,             lb0);
        GLDS16(gb + k0 + 64 * 1024, lb1);
        __syncthreads();
        v8s a[4], b[4];
#pragma unroll
        for (int mt = 0; mt < 4; mt++) a[mt] = *(const v8s*)&As[(wr*64 + mt*16 + l15)*32 + quad*8];
#pragma unroll
        for (int nt = 0; nt < 4; nt++) b[nt] = *(const v8s*)&Bs[(wc*64 + nt*16 + l15)*32 + quad*8];
#pragma unroll
        for (int mt = 0; mt < 4; mt++)
#pragma unroll
            for (int nt = 0; nt < 4; nt++)
                acc[mt][nt] = __builtin_amdgcn_mfma_f32_16x16x32_bf16(a[mt], b[nt], acc[mt][nt], 0, 0, 0);
    }

#pragma unroll
    for (int mt = 0; mt < 4; mt++) {
        const int mb = m0 + wr*64 + mt*16 + quad*4;
#pragma unroll
        for (int nt = 0; nt < 4; nt++) {
            const int n = n0 + wc*64 + nt*16 + l15;
            const float bias = bo[n];
#pragma unroll
            for (int r = 0; r < 4; r++)
                out[(mb + r)*1024 + n] = acc[mt][nt][r] + bias;
        }
    }
}

// ---------------------------------------------------------------------------
// FALLBACK GEMMs (fp32 inputs, cvt fused in staging)
// ---------------------------------------------------------------------------
__global__ __launch_bounds__(256)
void gemm_qkv(const float* __restrict__ x, const float* __restrict__ Wq,
              const float* __restrict__ Wk, const float* __restrict__ Wv,
              bf16* __restrict__ qd, bf16* __restrict__ kd, bf16* __restrict__ vtd)
{
    const int mode = blockIdx.z;
    const float* __restrict__ W = (mode == 0) ? Wq : (mode == 1) ? Wk : Wv;
    const int m0 = blockIdx.x * 128;
    const int n0 = blockIdx.y * 128;
    __shared__ bf16 As[128 * 40];
    __shared__ bf16 Bs[128 * 40];
    const int t    = threadIdx.x;
    const int lane = t & 63, w = t >> 6;
    const int wr = w >> 1, wc = w & 1;
    const int l15 = lane & 15, quad = lane >> 4;
    const int srow = t >> 2, scol = (t & 3) * 8;
    v4f acc[4][4] = {};

    for (int k0 = 0; k0 < 1024; k0 += 32) {
        __syncthreads();
        {
            const float* pa = &x[(m0 + srow) * 1024 + k0 + scol];
            *(v8s*)&As[srow*40 + scol] = pack_bf16x8(*(const float4*)pa, *(const float4*)(pa + 4));
            const float* pa2 = pa + 64 * 1024;
            *(v8s*)&As[(srow+64)*40 + scol] = pack_bf16x8(*(const float4*)pa2, *(const float4*)(pa2 + 4));
            const float* pb = &W[(n0 + srow) * 1024 + k0 + scol];
            *(v8s*)&Bs[srow*40 + scol] = pack_bf16x8(*(const float4*)pb, *(const float4*)(pb + 4));
            const float* pb2 = pb + 64 * 1024;
            *(v8s*)&Bs[(srow+64)*40 + scol] = pack_bf16x8(*(const float4*)pb2, *(const float4*)(pb2 + 4));
        }
        __syncthreads();
        v8s a[4], b[4];
#pragma unroll
        for (int mt = 0; mt < 4; mt++) a[mt] = *(const v8s*)&As[(wr*64 + mt*16 + l15)*40 + quad*8];
#pragma unroll
        for (int nt = 0; nt < 4; nt++) b[nt] = *(const v8s*)&Bs[(wc*64 + nt*16 + l15)*40 + quad*8];
#pragma unroll
        for (int mt = 0; mt < 4; mt++)
#pragma unroll
            for (int nt = 0; nt < 4; nt++)
                acc[mt][nt] = __builtin_amdgcn_mfma_f32_16x16x32_bf16(a[mt], b[nt], acc[mt][nt], 0, 0, 0);
    }

    const float qscale = (mode == 0) ? C2 : 1.0f;
#pragma unroll
    for (int mt = 0; mt < 4; mt++) {
        const int mb = m0 + wr*64 + mt*16 + quad*4;
        const int b_ = mb >> 11, s = mb & 2047;
#pragma unroll
        for (int nt = 0; nt < 4; nt++) {
            const int n = n0 + wc*64 + nt*16 + l15;
            const int h = n >> 6, d = n & 63;
            if (mode == 2) {
                unsigned int lo = (unsigned int)bf16_bits(__float2bfloat16(acc[mt][nt][0]))
                                | ((unsigned int)bf16_bits(__float2bfloat16(acc[mt][nt][1])) << 16);
                unsigned int hi = (unsigned int)bf16_bits(__float2bfloat16(acc[mt][nt][2]))
                                | ((unsigned int)bf16_bits(__float2bfloat16(acc[mt][nt][3])) << 16);
                uint2 pv; pv.x = lo; pv.y = hi;
                *(uint2*)&vtd[((b_*H_ + h)*HD_ + d)*S_ + s] = pv;
            } else {
                bf16* __restrict__ dst = (mode == 0) ? qd : kd;
#pragma unroll
                for (int r = 0; r < 4; r++)
                    dst[((b_*H_ + h)*S_ + (s + r))*HD_ + d] = __float2bfloat16(acc[mt][nt][r] * qscale);
            }
        }
    }
}

__global__ __launch_bounds__(256)
void gemm_out(const bf16* __restrict__ ctx, const float* __restrict__ Wo,
              const float* __restrict__ bo, float* __restrict__ out)
{
    const int m0 = blockIdx.x * 128;
    const int n0 = blockIdx.y * 128;
    __shared__ bf16 As[128 * 40];
    __shared__ bf16 Bs[128 * 40];
    const int t    = threadIdx.x;
    const int lane = t & 63, w = t >> 6;
    const int wr = w >> 1, wc = w & 1;
    const int l15 = lane & 15, quad = lane >> 4;
    const int srow = t >> 2, scol = (t & 3) * 8;
    v4f acc[4][4] = {};

    for (int k0 = 0; k0 < 1024; k0 += 32) {
        __syncthreads();
        {
            *(v8s*)&As[srow*40 + scol]      = *(const v8s*)&ctx[(m0+srow)*1024 + k0 + scol];
            *(v8s*)&As[(srow+64)*40 + scol] = *(const v8s*)&ctx[(m0+srow+64)*1024 + k0 + scol];
            const float* pb = &Wo[(n0 + srow) * 1024 + k0 + scol];
            *(v8s*)&Bs[srow*40 + scol] = pack_bf16x8(*(const float4*)pb, *(const float4*)(pb + 4));
            const float* pb2 = pb + 64 * 1024;
            *(v8s*)&Bs[(srow+64)*40 + scol] = pack_bf16x8(*(const float4*)pb2, *(const float4*)(pb2 + 4));
        }
        __syncthreads();
        v8s a[4], b[4];
#pragma unroll
        for (int mt = 0; mt < 4; mt++) a[mt] = *(const v8s*)&As[(wr*64 + mt*16 + l15)*40 + quad*8];
#pragma unroll
        for (int nt = 0; nt < 4; nt++) b[nt] = *(const v8s*)&Bs[(wc*64 + nt*16 + l15)*40 + quad*8];
#pragma unroll
        for (int mt = 0; mt < 4; mt++)
#pragma unroll
            for (int nt = 0; nt < 4; nt++)
                acc[mt][nt] = __builtin_amdgcn_mfma_f32_16x16x32_bf16(a[mt], b[nt], acc[mt][nt], 0, 0, 0);
    }

#pragma unroll
    for (int mt = 0; mt < 4; mt++) {
        const int mb = m0 + wr*64 + mt*16 + quad*4;
#pragma unroll
        for (int nt = 0; nt < 4; nt++) {
            const int n = n0 + wc*64 + nt*16 + l15;
            const float bias = bo[n];
#pragma unroll
            for (int r = 0; r < 4; r++)
                out[(mb + r)*1024 + n] = acc[mt][nt][r] + bias;
        }
    }
}

// ---------------------------------------------------------------------------
// Causal flash attention v8: latency-bound fix.
//  * 1024 blocks (32 bh x 32 q-slices of 64 rows), 256 thr, 1 row-grp/wave ->
//    3-4 co-resident blocks/CU (vs 2 waves/SIMD before); longest slices
//    dispatched first; dynamic refill balances the causal skew.
//  * Swapped QK^T (mfma(K,Q)): q is lane-local (q=l15); P->bf16 via
//    v_cvt_pk_bf16_f32 + 2-stage shfl_xor(32)/shfl_xor(16) relay network
//    rebuilds the PV A-operand IN REGISTERS -> no P LDS round-trip, no
//    lgkmcnt(0) drain mid-iteration.
//  * K fragments direct from global; next tile's loads issued right after
//    QK consumes the current ones (zero-extra-register prefetch).
//  * V tile in LDS, XOR-swizzled (elem ^= (row&7)<<3): conflict-free b128.
// ---------------------------------------------------------------------------
__global__ __launch_bounds__(256)
void flash_attn(const bf16* __restrict__ qd, const bf16* __restrict__ kd,
                const bf16* __restrict__ vtd, bf16* __restrict__ ctx)
{
    const int bh = blockIdx.x;               // 32 bh -> XCD = bh%8 (L2 locality)
    const int s  = 31 - (int)blockIdx.y;     // longest slices dispatched first
    const int t = threadIdx.x;
    const int lane = t & 63, w = t >> 6;     // 4 waves
    const int l15 = lane & 15, quad = lane >> 4;
    const int q0 = s * 64 + w * 16;          // wave's 16 q-rows
    const int nT = s + 1;

    __shared__ bf16 Vs[2][64 * 64];

    // Q fragment (B-operand: col=l15 -> q, k=quad*8+j -> d)
    const bf16* qp = qd + ((size_t)bh * S_ + q0 + l15) * HD_ + quad * 8;
    const v8s qf0 = *(const v8s*)qp;
    const v8s qf1 = *(const v8s*)(qp + 32);

    v4f o[4] = {};
    float ps = 0.0f;

    // V staging: 2 v8s per thread, XOR-swizzled LDS layout
    const int vrow = t >> 2, vc = (t & 3) * 16;
    const int wsw = (vrow & 7) << 3;
    const int vidx0 = (vrow * 64 + vc) ^ wsw;
    const int vidx1 = (vrow * 64 + vc + 8) ^ wsw;
    const bf16* vp = vtd + ((size_t)bh * HD_ + vrow) * S_ + vc;
    v8s pv0 = *(const v8s*)vp;
    v8s pv1 = *(const v8s*)(vp + 8);

    // K fragments (A-operand: row=l15 -> k-row, k=quad*8+j -> d), tile 0
    const bf16* kq = kd + ((size_t)bh * S_ + l15) * HD_ + quad * 8;
    v8s kf[4][2];
#pragma unroll
    for (int kt = 0; kt < 4; kt++) {
        kf[kt][0] = *(const v8s*)(kq + (kt * 16) * HD_);
        kf[kt][1] = *(const v8s*)(kq + (kt * 16) * HD_ + 32);
    }

    const int rsw = (l15 & 7) << 3;

    for (int it = 0; it < nT; ++it) {
        const int c0 = it * 64;
        bf16* Vb = &Vs[it & 1][0];
        *(v8s*)&Vb[vidx0] = pv0;
        *(v8s*)&Vb[vidx1] = pv1;
        __syncthreads();
        vp += 64;
        pv0 = *(const v8s*)vp;               // prefetch next V tile
        pv1 = *(const v8s*)(vp + 8);

        // V fragments (swizzled reads, conflict-free)
        v8s vf[4][2];
#pragma unroll
        for (int dt = 0; dt < 4; dt++) {
            const int rowd = dt * 16 + l15;
            vf[dt][0] = *(const v8s*)&Vb[(rowd * 64 + quad * 8) ^ rsw];
            vf[dt][1] = *(const v8s*)&Vb[(rowd * 64 + 32 + quad * 8) ^ rsw];
        }

        // QK^T swapped: sc[kt] reg r -> k = c0+kt*16+quad*4+r, q = q0+l15
        v4f sc[4];
#pragma unroll
        for (int kt = 0; kt < 4; kt++) {
            v4f z = {};
            z      = __builtin_amdgcn_mfma_f32_16x16x32_bf16(kf[kt][0], qf0, z, 0, 0, 0);
            sc[kt] = __builtin_amdgcn_mfma_f32_16x16x32_bf16(kf[kt][1], qf1, sc[kt] = z, 0, 0, 0);
        }

        // kf consumed -> issue next K tile loads (latency hides under exp+PV)
        if (it + 1 < nT) {
            const bf16* kn = kq + (size_t)(c0 + 64) * HD_;
#pragma unroll
            for (int kt = 0; kt < 4; kt++) {
                kf[kt][0] = *(const v8s*)(kn + (kt * 16) * HD_);
                kf[kt][1] = *(const v8s*)(kn + (kt * 16) * HD_ + 32);
            }
        }

        // mask (last tile only) + exp2 + row-sum (q=l15 is lane-local)
        if (c0 + 63 <= q0) {
#pragma unroll
            for (int kt = 0; kt < 4; kt++)
#pragma unroll
                for (int r = 0; r < 4; r++) {
                    const float p = EXP2F(sc[kt][r]);
                    sc[kt][r] = p; ps += p;
                }
        } else {
            const int kb = c0 - q0 - l15 + quad * 4;
#pragma unroll
            for (int kt = 0; kt < 4; kt++)
#pragma unroll
                for (int r = 0; r < 4; r++) {
                    const float sv = (kb + kt * 16 + r <= 0) ? sc[kt][r] : NEG_BIG;
                    const float p = EXP2F(sv);
                    sc[kt][r] = p; ps += p;
                }
        }

        // pack P -> bf16 pairs: W[kt][h] covers k = c0 + 16kt + 4quad + 2h
        unsigned W[4][2];
#pragma unroll
        for (int kt = 0; kt < 4; kt++) {
            CVT_PK(W[kt][0], sc[kt][0], sc[kt][1]);
            CVT_PK(W[kt][1], sc[kt][2], sc[kt][3]);
        }
        // 2-stage relay network -> pf (A-operand: row=l15=q, k=quad*8+j)
        const bool qhi = quad >= 2;
        unsigned X0 = qhi ? W[0][0] : W[1][0];
        unsigned X1 = qhi ? W[0][1] : W[1][1];
        unsigned X2 = qhi ? W[2][0] : W[3][0];
        unsigned X3 = qhi ? W[2][1] : W[3][1];
        const unsigned A0 = __shfl_xor(X0, 32);
        const unsigned A1 = __shfl_xor(X1, 32);
        const unsigned A2 = __shfl_xor(X2, 32);
        const unsigned A3 = __shfl_xor(X3, 32);
        unsigned Z0 = (quad == 1) ? W[0][0] : (quad == 2) ? W[1][0] : A0;
        unsigned Z1 = (quad == 1) ? W[0][1] : (quad == 2) ? W[1][1] : A1;
        unsigned Z2 = (quad == 1) ? W[2][0] : (quad == 2) ? W[3][0] : A2;
        unsigned Z3 = (quad == 1) ? W[2][1] : (quad == 2) ? W[3][1] : A3;
        const unsigned B0 = __shfl_xor(Z0, 16);
        const unsigned B1 = __shfl_xor(Z1, 16);
        const unsigned B2 = __shfl_xor(Z2, 16);
        const unsigned B3 = __shfl_xor(Z3, 16);
        union { v8s v; unsigned u[4]; } P0, P1;
        P0.u[0] = (quad == 0) ? W[0][0] : (quad == 2) ? A0 : B0;
        P0.u[1] = (quad == 0) ? W[0][1] : (quad == 2) ? A1 : B1;
        P0.u[2] = (quad == 3) ? W[1][0] : (quad == 1) ? A0 : B0;
        P0.u[3] = (quad == 3) ? W[1][1] : (quad == 1) ? A1 : B1;
        P1.u[0] = (quad == 0) ? W[2][0] : (quad == 2) ? A2 : B2;
        P1.u[1] = (quad == 0) ? W[2][1] : (quad == 2) ? A3 : B3;
        P1.u[2] = (quad == 3) ? W[3][0] : (quad == 1) ? A2 : B2;
        P1.u[3] = (quad == 3) ? W[3][1] : (quad == 1) ? A3 : B3;

        // PV
#pragma unroll
        for (int dt = 0; dt < 4; dt++) {
            o[dt] = __builtin_amdgcn_mfma_f32_16x16x32_bf16(P0.v, vf[dt][0], o[dt], 0, 0, 0);
            o[dt] = __builtin_amdgcn_mfma_f32_16x16x32_bf16(P1.v, vf[dt][1], o[dt], 0, 0, 0);
        }
    }

    // denominators: reduce partials across quads, then fetch per output row
    float dsum = ps + __shfl_xor(ps, 16);
    dsum += __shfl_xor(dsum, 32);
    const int b_ = bh >> 4, h = bh & 15;
#pragma unroll
    for (int r = 0; r < 4; r++) {
        const float linv = 1.0f / __shfl(dsum, quad * 4 + r);
        const int qg = q0 + quad * 4 + r;
#pragma unroll
        for (int dt = 0; dt < 4; dt++)
            ctx[((size_t)b_ * S_ + qg) * D_ + h * HD_ + dt * 16 + l15] =
                __float2bfloat16(o[dt][r] * linv);
    }
}

extern "C" void kernel_launch(void* const* d_in, const int* in_sizes, int n_in,
                              void* d_out, int out_size, void* d_ws, size_t ws_size,
                              hipStream_t stream) {
    const float* x  = (const float*)d_in[0];
    const float* Wq = (const float*)d_in[1];
    const float* Wk = (const float*)d_in[2];
    const float* Wv = (const float*)d_in[3];
    const float* Wo = (const float*)d_in[4];
    const float* bo = (const float*)d_in[5];
    float* out = (float*)d_out;

    const size_t SEG = (size_t)2 * H_ * S_ * HD_;      // 4 Mi bf16 elems = 8 MB
    bf16* qd  = (bf16*)d_ws;
    bf16* kd  = qd  + SEG;
    bf16* vtd = kd  + SEG;
    bf16* xc  = vtd + SEG;                             // x-bf16, later ctx
    bf16* wqb = xc + SEG;
    bf16* wkb = wqb + 1024 * 1024;
    bf16* wvb = wkb + 1024 * 1024;
    bf16* wob = wvb + 1024 * 1024;

    const size_t need_fast = (4 * SEG + 4 * 1024 * 1024) * sizeof(bf16);   // 40 MB

    if (ws_size >= need_fast) {
        cvt_bf16<<<dim3(2048, 5), 256, 0, stream>>>(x, Wq, Wk, Wv, Wo,
                                                    xc, wqb, wkb, wvb, wob);
        gemm_qkv_f<<<dim3(32, 8, 3), 256, 0, stream>>>(xc, wqb, wkb, wvb, qd, kd, vtd);
        flash_attn<<<dim3(32, 32), 256, 0, stream>>>(qd, kd, vtd, xc);   // xc = ctx
        gemm_out_f<<<dim3(32, 8), 256, 0, stream>>>(xc, wob, bo, out);
    } else {
        gemm_qkv<<<dim3(32, 8, 3), 256, 0, stream>>>(x, Wq, Wk, Wv, qd, kd, vtd);
        flash_attn<<<dim3(32, 32), 256, 0, stream>>>(qd, kd, vtd, xc);
        gemm_out<<<dim3(32, 8), 256, 0, stream>>>(xc, Wo, bo, out);
    }
}

// Round 3
// 222.324 us; speedup vs baseline: 1.0031x; 1.0031x over previous
//
#include <hip/hip_runtime.h>
#include <hip/hip_bf16.h>

typedef __hip_bfloat16 bf16;
typedef short v8s __attribute__((ext_vector_type(8)));
typedef float v4f __attribute__((ext_vector_type(4)));
typedef float v16f __attribute__((ext_vector_type(16)));

#define S_ 2048
#define D_ 1024
#define H_ 16
#define HD_ 64

#define EXP2F(x) __builtin_amdgcn_exp2f(x)   /* v_exp_f32: 2^x on gfx950 */
#define NEG_BIG (-1.0e30f)
#define C2 0.1803368801111244f   /* (1/sqrt(64)) * log2(e), folded into Q */

#define GLDS16(g, l) __builtin_amdgcn_global_load_lds(                        \
    (const __attribute__((address_space(1))) unsigned int*)(g),               \
    (__attribute__((address_space(3))) unsigned int*)(l), 16, 0, 0)

#define CVT_PK(d, lo, hi) \
    asm("v_cvt_pk_bf16_f32 %0, %1, %2" : "=v"(d) : "v"(lo), "v"(hi))

/* exchanges high 32 lanes of a with low 32 lanes of b (gfx950) */
#define SWAPHALF(a, b) \
    asm("v_permlane32_swap_b32 %0, %1" : "+v"(a), "+v"(b))

#define MFMA32(a, b, c) __builtin_amdgcn_mfma_f32_32x32x16_bf16(a, b, c, 0, 0, 0)

static __device__ __forceinline__ unsigned short bf16_bits(bf16 h) {
    union { bf16 h; unsigned short u; } c; c.h = h; return c.u;
}

static __device__ __forceinline__ v8s pack_bf16x8(const float4 a, const float4 b) {
    union { v8s v; unsigned short u[8]; } r;
    r.u[0] = bf16_bits(__float2bfloat16(a.x));
    r.u[1] = bf16_bits(__float2bfloat16(a.y));
    r.u[2] = bf16_bits(__float2bfloat16(a.z));
    r.u[3] = bf16_bits(__float2bfloat16(a.w));
    r.u[4] = bf16_bits(__float2bfloat16(b.x));
    r.u[5] = bf16_bits(__float2bfloat16(b.y));
    r.u[6] = bf16_bits(__float2bfloat16(b.z));
    r.u[7] = bf16_bits(__float2bfloat16(b.w));
    return r.v;
}

// ---------------------------------------------------------------------------
// fp32 -> bf16 conversion pre-pass
// ---------------------------------------------------------------------------
__global__ __launch_bounds__(256)
void cvt_bf16(const float* __restrict__ x,  const float* __restrict__ wq,
              const float* __restrict__ wk, const float* __restrict__ wv,
              const float* __restrict__ wo,
              bf16* __restrict__ xb,  bf16* __restrict__ wqb,
              bf16* __restrict__ wkb, bf16* __restrict__ wvb,
              bf16* __restrict__ wob)
{
    const int seg = blockIdx.y;
    const float* src; bf16* dst; int n;
    switch (seg) {
        case 0: src = x;  dst = xb;  n = 4096 * 1024; break;
        case 1: src = wq; dst = wqb; n = 1024 * 1024; break;
        case 2: src = wk; dst = wkb; n = 1024 * 1024; break;
        case 3: src = wv; dst = wvb; n = 1024 * 1024; break;
        default:src = wo; dst = wob; n = 1024 * 1024; break;
    }
    const int idx = (blockIdx.x * 256 + threadIdx.x) * 8;
    if (idx >= n) return;
    *(v8s*)&dst[idx] = pack_bf16x8(*(const float4*)&src[idx],
                                   *(const float4*)&src[idx + 4]);
}

// ---------------------------------------------------------------------------
// FAST NT GEMM (m97-style): bf16 inputs, global_load_lds width-16 staging.
// ---------------------------------------------------------------------------
__global__ __launch_bounds__(256)
void gemm_qkv_f(const bf16* __restrict__ xb, const bf16* __restrict__ wqb,
                const bf16* __restrict__ wkb, const bf16* __restrict__ wvb,
                bf16* __restrict__ qd, bf16* __restrict__ kd, bf16* __restrict__ vtd)
{
    const int mode = blockIdx.z;
    const bf16* __restrict__ W = (mode == 0) ? wqb : (mode == 1) ? wkb : wvb;
    const int m0 = blockIdx.x * 128;
    const int n0 = blockIdx.y * 128;
    __shared__ bf16 As[128 * 32];
    __shared__ bf16 Bs[128 * 32];
    const int t    = threadIdx.x;
    const int lane = t & 63, w = t >> 6;
    const int wr = w >> 1, wc = w & 1;
    const int l15 = lane & 15, quad = lane >> 4;
    const int r16 = lane >> 2, c8 = (lane & 3) * 8;
    v4f acc[4][4] = {};

    const bf16* ga = &xb[(m0 + w*16 + r16) * 1024 + c8];
    const bf16* gb = &W [(n0 + w*16 + r16) * 1024 + c8];
    bf16* la0 = &As[w * 16 * 32];
    bf16* la1 = &As[(64 + w * 16) * 32];
    bf16* lb0 = &Bs[w * 16 * 32];
    bf16* lb1 = &Bs[(64 + w * 16) * 32];

    for (int k0 = 0; k0 < 1024; k0 += 32) {
        __syncthreads();
        GLDS16(ga + k0,             la0);
        GLDS16(ga + k0 + 64 * 1024, la1);
        GLDS16(gb + k0,             lb0);
        GLDS16(gb + k0 + 64 * 1024, lb1);
        __syncthreads();
        v8s a[4], b[4];
#pragma unroll
        for (int mt = 0; mt < 4; mt++) a[mt] = *(const v8s*)&As[(wr*64 + mt*16 + l15)*32 + quad*8];
#pragma unroll
        for (int nt = 0; nt < 4; nt++) b[nt] = *(const v8s*)&Bs[(wc*64 + nt*16 + l15)*32 + quad*8];
#pragma unroll
        for (int mt = 0; mt < 4; mt++)
#pragma unroll
            for (int nt = 0; nt < 4; nt++)
                acc[mt][nt] = __builtin_amdgcn_mfma_f32_16x16x32_bf16(a[mt], b[nt], acc[mt][nt], 0, 0, 0);
    }

    const float qscale = (mode == 0) ? C2 : 1.0f;
#pragma unroll
    for (int mt = 0; mt < 4; mt++) {
        const int mb = m0 + wr*64 + mt*16 + quad*4;
        const int b_ = mb >> 11, s = mb & 2047;
#pragma unroll
        for (int nt = 0; nt < 4; nt++) {
            const int n = n0 + wc*64 + nt*16 + l15;
            const int h = n >> 6, d = n & 63;
            if (mode == 2) {
                unsigned int lo = (unsigned int)bf16_bits(__float2bfloat16(acc[mt][nt][0]))
                                | ((unsigned int)bf16_bits(__float2bfloat16(acc[mt][nt][1])) << 16);
                unsigned int hi = (unsigned int)bf16_bits(__float2bfloat16(acc[mt][nt][2]))
                                | ((unsigned int)bf16_bits(__float2bfloat16(acc[mt][nt][3])) << 16);
                uint2 pv; pv.x = lo; pv.y = hi;
                *(uint2*)&vtd[((b_*H_ + h)*HD_ + d)*S_ + s] = pv;
            } else {
                bf16* __restrict__ dst = (mode == 0) ? qd : kd;
#pragma unroll
                for (int r = 0; r < 4; r++)
                    dst[((b_*H_ + h)*S_ + (s + r))*HD_ + d] = __float2bfloat16(acc[mt][nt][r] * qscale);
            }
        }
    }
}

__global__ __launch_bounds__(256)
void gemm_out_f(const bf16* __restrict__ ctx, const bf16* __restrict__ wob,
                const float* __restrict__ bo, float* __restrict__ out)
{
    const int m0 = blockIdx.x * 128;
    const int n0 = blockIdx.y * 128;
    __shared__ bf16 As[128 * 32];
    __shared__ bf16 Bs[128 * 32];
    const int t    = threadIdx.x;
    const int lane = t & 63, w = t >> 6;
    const int wr = w >> 1, wc = w & 1;
    const int l15 = lane & 15, quad = lane >> 4;
    const int r16 = lane >> 2, c8 = (lane & 3) * 8;
    v4f acc[4][4] = {};

    const bf16* ga = &ctx[(m0 + w*16 + r16) * 1024 + c8];
    const bf16* gb = &wob[(n0 + w*16 + r16) * 1024 + c8];
    bf16* la0 = &As[w * 16 * 32];
    bf16* la1 = &As[(64 + w * 16) * 32];
    bf16* lb0 = &Bs[w * 16 * 32];
    bf16* lb1 = &Bs[(64 + w * 16) * 32];

    for (int k0 = 0; k0 < 1024; k0 += 32) {
        __syncthreads();
        GLDS16(ga + k0,             la0);
        GLDS16(ga + k0 + 64 * 1024, la1);
        GLDS16(gb + k0,             lb0);
        GLDS16(gb + k0 + 64 * 1024, lb1);
        __syncthreads();
        v8s a[4], b[4];
#pragma unroll
        for (int mt = 0; mt < 4; mt++) a[mt] = *(const v8s*)&As[(wr*64 + mt*16 + l15)*32 + quad*8];
#pragma unroll
        for (int nt = 0; nt < 4; nt++) b[nt] = *(const v8s*)&Bs[(wc*64 + nt*16 + l15)*32 + quad*8];
#pragma unroll
        for (int mt = 0; mt < 4; mt++)
#pragma unroll
            for (int nt = 0; nt < 4; nt++)
                acc[mt][nt] = __builtin_amdgcn_mfma_f32_16x16x32_bf16(a[mt], b[nt], acc[mt][nt], 0, 0, 0);
    }

#pragma unroll
    for (int mt = 0; mt < 4; mt++) {
        const int mb = m0 + wr*64 + mt*16 + quad*4;
#pragma unroll
        for (int nt = 0; nt < 4; nt++) {
            const int n = n0 + wc*64 + nt*16 + l15;
            const float bias = bo[n];
#pragma unroll
            for (int r = 0; r < 4; r++)
                out[(mb + r)*1024 + n] = acc[mt][nt][r] + bias;
        }
    }
}

// ---------------------------------------------------------------------------
// FALLBACK GEMMs (fp32 inputs, cvt fused in staging)
// ---------------------------------------------------------------------------
__global__ __launch_bounds__(256)
void gemm_qkv(const float* __restrict__ x, const float* __restrict__ Wq,
              const float* __restrict__ Wk, const float* __restrict__ Wv,
              bf16* __restrict__ qd, bf16* __restrict__ kd, bf16* __restrict__ vtd)
{
    const int mode = blockIdx.z;
    const float* __restrict__ W = (mode == 0) ? Wq : (mode == 1) ? Wk : Wv;
    const int m0 = blockIdx.x * 128;
    const int n0 = blockIdx.y * 128;
    __shared__ bf16 As[128 * 40];
    __shared__ bf16 Bs[128 * 40];
    const int t    = threadIdx.x;
    const int lane = t & 63, w = t >> 6;
    const int wr = w >> 1, wc = w & 1;
    const int l15 = lane & 15, quad = lane >> 4;
    const int srow = t >> 2, scol = (t & 3) * 8;
    v4f acc[4][4] = {};

    for (int k0 = 0; k0 < 1024; k0 += 32) {
        __syncthreads();
        {
            const float* pa = &x[(m0 + srow) * 1024 + k0 + scol];
            *(v8s*)&As[srow*40 + scol] = pack_bf16x8(*(const float4*)pa, *(const float4*)(pa + 4));
            const float* pa2 = pa + 64 * 1024;
            *(v8s*)&As[(srow+64)*40 + scol] = pack_bf16x8(*(const float4*)pa2, *(const float4*)(pa2 + 4));
            const float* pb = &W[(n0 + srow) * 1024 + k0 + scol];
            *(v8s*)&Bs[srow*40 + scol] = pack_bf16x8(*(const float4*)pb, *(const float4*)(pb + 4));
            const float* pb2 = pb + 64 * 1024;
            *(v8s*)&Bs[(srow+64)*40 + scol] = pack_bf16x8(*(const float4*)pb2, *(const float4*)(pb2 + 4));
        }
        __syncthreads();
        v8s a[4], b[4];
#pragma unroll
        for (int mt = 0; mt < 4; mt++) a[mt] = *(const v8s*)&As[(wr*64 + mt*16 + l15)*40 + quad*8];
#pragma unroll
        for (int nt = 0; nt < 4; nt++) b[nt] = *(const v8s*)&Bs[(wc*64 + nt*16 + l15)*40 + quad*8];
#pragma unroll
        for (int mt = 0; mt < 4; mt++)
#pragma unroll
            for (int nt = 0; nt < 4; nt++)
                acc[mt][nt] = __builtin_amdgcn_mfma_f32_16x16x32_bf16(a[mt], b[nt], acc[mt][nt], 0, 0, 0);
    }

    const float qscale = (mode == 0) ? C2 : 1.0f;
#pragma unroll
    for (int mt = 0; mt < 4; mt++) {
        const int mb = m0 + wr*64 + mt*16 + quad*4;
        const int b_ = mb >> 11, s = mb & 2047;
#pragma unroll
        for (int nt = 0; nt < 4; nt++) {
            const int n = n0 + wc*64 + nt*16 + l15;
            const int h = n >> 6, d = n & 63;
            if (mode == 2) {
                unsigned int lo = (unsigned int)bf16_bits(__float2bfloat16(acc[mt][nt][0]))
                                | ((unsigned int)bf16_bits(__float2bfloat16(acc[mt][nt][1])) << 16);
                unsigned int hi = (unsigned int)bf16_bits(__float2bfloat16(acc[mt][nt][2]))
                                | ((unsigned int)bf16_bits(__float2bfloat16(acc[mt][nt][3])) << 16);
                uint2 pv; pv.x = lo; pv.y = hi;
                *(uint2*)&vtd[((b_*H_ + h)*HD_ + d)*S_ + s] = pv;
            } else {
                bf16* __restrict__ dst = (mode == 0) ? qd : kd;
#pragma unroll
                for (int r = 0; r < 4; r++)
                    dst[((b_*H_ + h)*S_ + (s + r))*HD_ + d] = __float2bfloat16(acc[mt][nt][r] * qscale);
            }
        }
    }
}

__global__ __launch_bounds__(256)
void gemm_out(const bf16* __restrict__ ctx, const float* __restrict__ Wo,
              const float* __restrict__ bo, float* __restrict__ out)
{
    const int m0 = blockIdx.x * 128;
    const int n0 = blockIdx.y * 128;
    __shared__ bf16 As[128 * 40];
    __shared__ bf16 Bs[128 * 40];
    const int t    = threadIdx.x;
    const int lane = t & 63, w = t >> 6;
    const int wr = w >> 1, wc = w & 1;
    const int l15 = lane & 15, quad = lane >> 4;
    const int srow = t >> 2, scol = (t & 3) * 8;
    v4f acc[4][4] = {};

    for (int k0 = 0; k0 < 1024; k0 += 32) {
        __syncthreads();
        {
            *(v8s*)&As[srow*40 + scol]      = *(const v8s*)&ctx[(m0+srow)*1024 + k0 + scol];
            *(v8s*)&As[(srow+64)*40 + scol] = *(const v8s*)&ctx[(m0+srow+64)*1024 + k0 + scol];
            const float* pb = &Wo[(n0 + srow) * 1024 + k0 + scol];
            *(v8s*)&Bs[srow*40 + scol] = pack_bf16x8(*(const float4*)pb, *(const float4*)(pb + 4));
            const float* pb2 = pb + 64 * 1024;
            *(v8s*)&Bs[(srow+64)*40 + scol] = pack_bf16x8(*(const float4*)pb2, *(const float4*)(pb2 + 4));
        }
        __syncthreads();
        v8s a[4], b[4];
#pragma unroll
        for (int mt = 0; mt < 4; mt++) a[mt] = *(const v8s*)&As[(wr*64 + mt*16 + l15)*40 + quad*8];
#pragma unroll
        for (int nt = 0; nt < 4; nt++) b[nt] = *(const v8s*)&Bs[(wc*64 + nt*16 + l15)*40 + quad*8];
#pragma unroll
        for (int mt = 0; mt < 4; mt++)
#pragma unroll
            for (int nt = 0; nt < 4; nt++)
                acc[mt][nt] = __builtin_amdgcn_mfma_f32_16x16x32_bf16(a[mt], b[nt], acc[mt][nt], 0, 0, 0);
    }

#pragma unroll
    for (int mt = 0; mt < 4; mt++) {
        const int mb = m0 + wr*64 + mt*16 + quad*4;
#pragma unroll
        for (int nt = 0; nt < 4; nt++) {
            const int n = n0 + wc*64 + nt*16 + l15;
            const float bias = bo[n];
#pragma unroll
            for (int r = 0; r < 4; r++)
                out[(mb + r)*1024 + n] = acc[mt][nt][r] + bias;
        }
    }
}

// ---------------------------------------------------------------------------
// Causal flash attention v9: 32x32 MFMA, zero LDS, zero barriers.
//  * One wave per 32 q-rows; grid 32 bh x 64 slices = 2048 independent
//    single-wave blocks (longest first, dynamic refill balance).
//  * Swapped QK^T (mfma_32x32x16(K,Q)): lane holds P for q=lane&31,
//    k=(reg&3)+8*(reg>>2)+4*hi. PV A-operand rebuilt IN REGISTERS with
//    16 v_cvt_pk_bf16_f32 + 8 v_permlane32_swap_b32 (no LDS, no bpermute).
//  * K, V^T, Q fragments all read directly from global as coalesced 16B
//    (L2-resident, bh -> XCD locality); next K tile prefetched right after
//    the QK MFMAs consume the current one.
//  * s_setprio(1) around MFMA clusters (independent-wave regime, T5).
// ---------------------------------------------------------------------------
#define SOFTMAX_PV(sa, ks0, vA0, vA1, vB0, vB1)                                \
    {                                                                          \
        const bool full_ = ((ks0) + 31 <= q0);                                 \
        if (full_) {                                                           \
            _Pragma("unroll")                                                  \
            for (int r = 0; r < 16; r++) {                                     \
                const float p = EXP2F(sa[r]); sa[r] = p;                       \
                if (r & 1) ps1 += p; else ps0 += p;                            \
            }                                                                  \
        } else {                                                               \
            const int kb_ = (ks0) + 4 * hi - q0 - l31;                         \
            _Pragma("unroll")                                                  \
            for (int r = 0; r < 16; r++) {                                     \
                const int kl_ = (r & 3) + 8 * (r >> 2);                        \
                const float p = EXP2F((kb_ + kl_ <= 0) ? sa[r] : NEG_BIG);     \
                sa[r] = p;                                                     \
                if (r & 1) ps1 += p; else ps0 += p;                            \
            }                                                                  \
        }                                                                      \
        unsigned u0, u1, u2, u3, u4, u5, u6, u7;                               \
        CVT_PK(u0, sa[0],  sa[1]);  CVT_PK(u1, sa[2],  sa[3]);                 \
        CVT_PK(u2, sa[4],  sa[5]);  CVT_PK(u3, sa[6],  sa[7]);                 \
        CVT_PK(u4, sa[8],  sa[9]);  CVT_PK(u5, sa[10], sa[11]);                \
        CVT_PK(u6, sa[12], sa[13]); CVT_PK(u7, sa[14], sa[15]);                \
        SWAPHALF(u0, u2); SWAPHALF(u1, u3);                                    \
        SWAPHALF(u4, u6); SWAPHALF(u5, u7);                                    \
        union { v8s v; unsigned w[4]; } pa0_, pa1_;                            \
        pa0_.w[0] = u0; pa0_.w[1] = u1; pa0_.w[2] = u2; pa0_.w[3] = u3;        \
        pa1_.w[0] = u4; pa1_.w[1] = u5; pa1_.w[2] = u6; pa1_.w[3] = u7;        \
        __builtin_amdgcn_s_setprio(1);                                         \
        o0 = MFMA32(pa0_.v, vA0, o0);                                          \
        o1 = MFMA32(pa0_.v, vB0, o1);                                          \
        o0 = MFMA32(pa1_.v, vA1, o0);                                          \
        o1 = MFMA32(pa1_.v, vB1, o1);                                          \
        __builtin_amdgcn_s_setprio(0);                                         \
    }

__global__ __launch_bounds__(64)
void flash_attn(const bf16* __restrict__ qd, const bf16* __restrict__ kd,
                const bf16* __restrict__ vtd, bf16* __restrict__ ctx)
{
    const int bh = blockIdx.x;               // 0..31 -> XCD locality for K/V
    const int m  = 63 - (int)blockIdx.y;     // longest slices first
    const int lane = threadIdx.x;
    const int l31 = lane & 31, hi = lane >> 5;
    const int q0 = m * 32;
    const int nT = (q0 >> 6) + 1;

    // Q B-frags (col=q=l31, k-elem=d=hi*8+j+16*dk), resident whole kernel
    const bf16* qp = qd + ((size_t)bh * S_ + q0 + l31) * HD_ + hi * 8;
    const v8s qf0 = *(const v8s*)(qp);
    const v8s qf1 = *(const v8s*)(qp + 16);
    const v8s qf2 = *(const v8s*)(qp + 32);
    const v8s qf3 = *(const v8s*)(qp + 48);

    v16f o0 = {}, o1 = {};                   // d = l31 / l31+32; q via regs
    float ps0 = 0.f, ps1 = 0.f;

    const bf16* kq  = kd  + ((size_t)bh * S_ + l31) * HD_ + hi * 8;
    const bf16* vb0 = vtd + ((size_t)bh * HD_ + l31) * S_ + hi * 8;
    const bf16* vb1 = vb0 + (size_t)32 * S_;

    // K A-frags for tile 0 (row=k=l31, k-elem=d)
    v8s kA0 = *(const v8s*)(kq);
    v8s kA1 = *(const v8s*)(kq + 16);
    v8s kA2 = *(const v8s*)(kq + 32);
    v8s kA3 = *(const v8s*)(kq + 48);
    v8s kB0 = *(const v8s*)(kq + 32 * HD_);
    v8s kB1 = *(const v8s*)(kq + 32 * HD_ + 16);
    v8s kB2 = *(const v8s*)(kq + 32 * HD_ + 32);
    v8s kB3 = *(const v8s*)(kq + 32 * HD_ + 48);

    for (int it = 0; it < nT; ++it) {
        const int c0 = it * 64;
        const bool a1 = (c0 + 32 <= q0 + 31);

        // V B-frags for this tile (issue early; consumed at PV ~300cyc later)
        const bf16* v0 = vb0 + c0;
        const bf16* v1 = vb1 + c0;
        const v8s va00 = *(const v8s*)(v0);        // sub0 kh0 dt0
        const v8s va01 = *(const v8s*)(v0 + 16);   // sub0 kh1 dt0
        const v8s vc00 = *(const v8s*)(v1);        // sub0 kh0 dt1
        const v8s vc01 = *(const v8s*)(v1 + 16);
        const v8s va10 = *(const v8s*)(v0 + 32);   // sub1 kh0 dt0
        const v8s va11 = *(const v8s*)(v0 + 48);
        const v8s vc10 = *(const v8s*)(v1 + 32);
        const v8s vc11 = *(const v8s*)(v1 + 48);

        __builtin_amdgcn_s_setprio(1);
        v16f sa0 = {};
        sa0 = MFMA32(kA0, qf0, sa0);
        sa0 = MFMA32(kA1, qf1, sa0);
        sa0 = MFMA32(kA2, qf2, sa0);
        sa0 = MFMA32(kA3, qf3, sa0);
        v16f sa1 = {};
        if (a1) {
            sa1 = MFMA32(kB0, qf0, sa1);
            sa1 = MFMA32(kB1, qf1, sa1);
            sa1 = MFMA32(kB2, qf2, sa1);
            sa1 = MFMA32(kB3, qf3, sa1);
        }
        __builtin_amdgcn_s_setprio(0);

        // kf consumed -> prefetch next K tile into the same registers
        if (it + 1 < nT) {
            const bf16* kn = kq + (size_t)(c0 + 64) * HD_;
            kA0 = *(const v8s*)(kn);
            kA1 = *(const v8s*)(kn + 16);
            kA2 = *(const v8s*)(kn + 32);
            kA3 = *(const v8s*)(kn + 48);
            kB0 = *(const v8s*)(kn + 32 * HD_);
            kB1 = *(const v8s*)(kn + 32 * HD_ + 16);
            kB2 = *(const v8s*)(kn + 32 * HD_ + 32);
            kB3 = *(const v8s*)(kn + 32 * HD_ + 48);
        }

        SOFTMAX_PV(sa0, c0, va00, va01, vc00, vc01);
        if (a1) SOFTMAX_PV(sa1, c0 + 32, va10, va11, vc10, vc11);
    }

    // denominator for q=l31: this lane's half + the other hi half
    const float ps = ps0 + ps1;
    const float tot = ps + __shfl_xor(ps, 32);
    const int b_ = bh >> 4, hh = bh & 15;
    bf16* cb = ctx + ((size_t)b_ * S_ + q0) * D_ + hh * HD_ + l31;
#pragma unroll
    for (int r = 0; r < 16; r++) {
        const int qr = (r & 3) + 8 * (r >> 2) + 4 * hi;
        const float linv = 1.0f / __shfl(tot, qr);
        cb[(size_t)qr * D_]      = __float2bfloat16(o0[r] * linv);
        cb[(size_t)qr * D_ + 32] = __float2bfloat16(o1[r] * linv);
    }
}

extern "C" void kernel_launch(void* const* d_in, const int* in_sizes, int n_in,
                              void* d_out, int out_size, void* d_ws, size_t ws_size,
                              hipStream_t stream) {
    const float* x  = (const float*)d_in[0];
    const float* Wq = (const float*)d_in[1];
    const float* Wk = (const float*)d_in[2];
    const float* Wv = (const float*)d_in[3];
    const float* Wo = (const float*)d_in[4];
    const float* bo = (const float*)d_in[5];
    float* out = (float*)d_out;

    const size_t SEG = (size_t)2 * H_ * S_ * HD_;      // 4 Mi bf16 elems = 8 MB
    bf16* qd  = (bf16*)d_ws;
    bf16* kd  = qd  + SEG;
    bf16* vtd = kd  + SEG;
    bf16* xc  = vtd + SEG;                             // x-bf16, later ctx
    bf16* wqb = xc + SEG;
    bf16* wkb = wqb + 1024 * 1024;
    bf16* wvb = wkb + 1024 * 1024;
    bf16* wob = wvb + 1024 * 1024;

    const size_t need_fast = (4 * SEG + 4 * 1024 * 1024) * sizeof(bf16);   // 40 MB

    if (ws_size >= need_fast) {
        cvt_bf16<<<dim3(2048, 5), 256, 0, stream>>>(x, Wq, Wk, Wv, Wo,
                                                    xc, wqb, wkb, wvb, wob);
        gemm_qkv_f<<<dim3(32, 8, 3), 256, 0, stream>>>(xc, wqb, wkb, wvb, qd, kd, vtd);
        flash_attn<<<dim3(32, 64), 64, 0, stream>>>(qd, kd, vtd, xc);   // xc = ctx
        gemm_out_f<<<dim3(32, 8), 256, 0, stream>>>(xc, wob, bo, out);
    } else {
        gemm_qkv<<<dim3(32, 8, 3), 256, 0, stream>>>(x, Wq, Wk, Wv, qd, kd, vtd);
        flash_attn<<<dim3(32, 64), 64, 0, stream>>>(qd, kd, vtd, xc);
        gemm_out<<<dim3(32, 8), 256, 0, stream>>>(xc, Wo, bo, out);
    }
}

// Round 4
// 211.587 us; speedup vs baseline: 1.0540x; 1.0507x over previous
//
#include <hip/hip_runtime.h>
#include <hip/hip_bf16.h>

typedef __hip_bfloat16 bf16;
typedef short v8s __attribute__((ext_vector_type(8)));
typedef float v4f __attribute__((ext_vector_type(4)));

#define S_ 2048
#define D_ 1024
#define H_ 16
#define HD_ 64

#define EXP2F(x) __builtin_amdgcn_exp2f(x)   /* v_exp_f32: 2^x on gfx950 */
#define NEG_BIG (-1.0e30f)
#define C2 0.1803368801111244f   /* (1/sqrt(64)) * log2(e), folded into Q */

#define GLDS16(g, l) __builtin_amdgcn_global_load_lds(                        \
    (const __attribute__((address_space(1))) unsigned int*)(g),               \
    (__attribute__((address_space(3))) unsigned int*)(l), 16, 0, 0)

static __device__ __forceinline__ unsigned short bf16_bits(bf16 h) {
    union { bf16 h; unsigned short u; } c; c.h = h; return c.u;
}

static __device__ __forceinline__ v8s pack_bf16x8(const float4 a, const float4 b) {
    union { v8s v; unsigned short u[8]; } r;
    r.u[0] = bf16_bits(__float2bfloat16(a.x));
    r.u[1] = bf16_bits(__float2bfloat16(a.y));
    r.u[2] = bf16_bits(__float2bfloat16(a.z));
    r.u[3] = bf16_bits(__float2bfloat16(a.w));
    r.u[4] = bf16_bits(__float2bfloat16(b.x));
    r.u[5] = bf16_bits(__float2bfloat16(b.y));
    r.u[6] = bf16_bits(__float2bfloat16(b.z));
    r.u[7] = bf16_bits(__float2bfloat16(b.w));
    return r.v;
}

// ---------------------------------------------------------------------------
// fp32 -> bf16 conversion pre-pass
// ---------------------------------------------------------------------------
__global__ __launch_bounds__(256)
void cvt_bf16(const float* __restrict__ x,  const float* __restrict__ wq,
              const float* __restrict__ wk, const float* __restrict__ wv,
              const float* __restrict__ wo,
              bf16* __restrict__ xb,  bf16* __restrict__ wqb,
              bf16* __restrict__ wkb, bf16* __restrict__ wvb,
              bf16* __restrict__ wob)
{
    const int seg = blockIdx.y;
    const float* src; bf16* dst; int n;
    switch (seg) {
        case 0: src = x;  dst = xb;  n = 4096 * 1024; break;
        case 1: src = wq; dst = wqb; n = 1024 * 1024; break;
        case 2: src = wk; dst = wkb; n = 1024 * 1024; break;
        case 3: src = wv; dst = wvb; n = 1024 * 1024; break;
        default:src = wo; dst = wob; n = 1024 * 1024; break;
    }
    const int idx = (blockIdx.x * 256 + threadIdx.x) * 8;
    if (idx >= n) return;
    *(v8s*)&dst[idx] = pack_bf16x8(*(const float4*)&src[idx],
                                   *(const float4*)&src[idx + 4]);
}

// ---------------------------------------------------------------------------
// QKV GEMM, 256x256 8-phase schedule (T3+T4+T5, linear LDS / m198 config):
// BK=64, 512 threads (8 waves = 2M x 4N), per-wave C = 128x64.
// LDS 128KB: A/B x 2 K-tile buffers x 2 halves x [128][64] bf16.
// Per phase: ds-read one register subtile, issue 1 half-tile global_load_lds
// prefetch, raw s_barrier, setprio(1), 16 MFMA, setprio(0), raw s_barrier.
// Counted s_waitcnt vmcnt(2) ONLY at phases 4 and 8 (never 0 in the loop):
// staged half-tiles stay in flight across barriers (the m97-killer).
// Stage schedule per iteration i (computes tiles 2i->buf0, 2i+1->buf1):
//   ph1-3 stage tile 2i+1 {A1,B0,B1}->buf1 (its A0 went in prev ph8),
//   ph4-7 stage tile 2i+2 {A0,A1,B0,B1}->buf0, ph8 stages tile 2i+3 A0->buf1.
// Reads of a buffer complete (lgkm before MFMA) before the phase-end barrier,
// so the overwriting stage (2+ phases later) can never race them.
// Tail iterations stage past K=1024: reads land in adjacent ws buffers
// (harmless garbage, never consumed) -> waits stay uniform.
// ---------------------------------------------------------------------------
static __device__ __forceinline__ void stage_half(bf16* ldsbase, const bf16* gbase,
                                                  int w, int l) {
    const int r = l >> 3, c = (l & 7) * 8;   // lane covers row seg*8+r, col c..c+7
    GLDS16(gbase + (size_t)((2 * w + 0) * 8 + r) * 1024 + c, ldsbase + (2 * w + 0) * 512);
    GLDS16(gbase + (size_t)((2 * w + 1) * 8 + r) * 1024 + c, ldsbase + (2 * w + 1) * 512);
}

#define MF16(a, b, c) __builtin_amdgcn_mfma_f32_16x16x32_bf16(a, b, c, 0, 0, 0)

#define LDA(buf, mf0) { _Pragma("unroll") for (int m_ = 0; m_ < 4; ++m_) {     \
    af[m_][0] = *(const v8s*)&AsS[(buf)*16384 + abase + ((mf0) + m_)*1024];    \
    af[m_][1] = *(const v8s*)&AsS[(buf)*16384 + abase + ((mf0) + m_)*1024 + 32]; } }
#define LDB0(buf) { _Pragma("unroll") for (int n_ = 0; n_ < 2; ++n_) {         \
    b0f[n_][0] = *(const v8s*)&BsS[(buf)*16384 + bbase + n_*1024];             \
    b0f[n_][1] = *(const v8s*)&BsS[(buf)*16384 + bbase + n_*1024 + 32]; } }
#define LDB1(buf) { _Pragma("unroll") for (int n_ = 0; n_ < 2; ++n_) {         \
    b1f[n_][0] = *(const v8s*)&BsS[(buf)*16384 + bbase + (2 + n_)*1024];       \
    b1f[n_][1] = *(const v8s*)&BsS[(buf)*16384 + bbase + (2 + n_)*1024 + 32]; } }
#define MMQ(MH, NH, AF, BF) { _Pragma("unroll") for (int m_ = 0; m_ < 4; ++m_) \
    _Pragma("unroll") for (int n_ = 0; n_ < 2; ++n_) {                         \
      acc[(MH)*4 + m_][(NH)*2 + n_] =                                          \
        MF16(AF[m_][0], BF[n_][0], acc[(MH)*4 + m_][(NH)*2 + n_]);             \
      acc[(MH)*4 + m_][(NH)*2 + n_] =                                          \
        MF16(AF[m_][1], BF[n_][1], acc[(MH)*4 + m_][(NH)*2 + n_]); } }
#define BAR() __builtin_amdgcn_s_barrier()
#define VMC2() asm volatile("s_waitcnt vmcnt(2)" ::: "memory")
#define PRIO1() __builtin_amdgcn_s_setprio(1)
#define PRIO0() __builtin_amdgcn_s_setprio(0)

__global__ __launch_bounds__(512, 2)
void gemm_qkv_8p(const bf16* __restrict__ xb, const bf16* __restrict__ wqb,
                 const bf16* __restrict__ wkb, const bf16* __restrict__ wvb,
                 bf16* __restrict__ qd, bf16* __restrict__ kd, bf16* __restrict__ vtd)
{
    __shared__ bf16 AsS[2 * 16384];          // [buf][half 128][64]
    __shared__ bf16 BsS[2 * 16384];
    const int mode = blockIdx.z;
    const bf16* __restrict__ W = (mode == 0) ? wqb : (mode == 1) ? wkb : wvb;
    const int m0 = blockIdx.x * 256;
    const int n0 = blockIdx.y * 256;
    const int t = threadIdx.x;
    const int lane = t & 63, w = t >> 6;
    const int wr = w >> 2, wc = w & 3;       // 2M x 4N waves
    const int l15 = lane & 15, quad = lane >> 4;
    const int abase = wr * 8192 + l15 * 64 + quad * 8;
    const int bbase = (wc >> 1) * 8192 + (wc & 1) * 4096 + l15 * 64 + quad * 8;
    const bf16* Aap = xb + (size_t)m0 * 1024;
    const bf16* Bbp = W + (size_t)n0 * 1024;

    v4f acc[8][4] = {};
    v8s af[4][2], b0f[2][2], b1f[2][2];

    // prologue: tile0 (buf0, 4 halves) + tile1 A0 (buf1); keep tile1-A0 in flight
    stage_half(AsS,          Aap,          w, lane);
    stage_half(AsS + 8192,   Aap + 131072, w, lane);
    stage_half(BsS,          Bbp,          w, lane);
    stage_half(BsS + 8192,   Bbp + 131072, w, lane);
    stage_half(AsS + 16384,  Aap + 64,     w, lane);
    VMC2();
    BAR();

    for (int i = 0; i < 8; ++i) {
        const int kc = i * 128;
        // ph1: buf0 A-mh0 + B-nh0; stage tile(2i+1) A1 -> buf1
        LDA(0, 0); LDB0(0);
        stage_half(AsS + 16384 + 8192, Aap + 131072 + kc + 64, w, lane);
        BAR(); PRIO1(); MMQ(0, 0, af, b0f); PRIO0(); BAR();
        // ph2: buf0 B-nh1; stage tile(2i+1) B0 -> buf1
        LDB1(0);
        stage_half(BsS + 16384, Bbp + kc + 64, w, lane);
        BAR(); PRIO1(); MMQ(0, 1, af, b1f); PRIO0(); BAR();
        // ph3: buf0 A-mh1; stage tile(2i+1) B1 -> buf1
        LDA(0, 4);
        stage_half(BsS + 16384 + 8192, Bbp + 131072 + kc + 64, w, lane);
        BAR(); PRIO1(); MMQ(1, 1, af, b1f); PRIO0(); BAR();
        // ph4: stage tile(2i+2) A0 -> buf0; counted wait for tile(2i+1)
        stage_half(AsS, Aap + kc + 128, w, lane);
        VMC2();
        BAR(); PRIO1(); MMQ(1, 0, af, b0f); PRIO0(); BAR();
        // ph5: buf1 A-mh0 + B-nh0; stage tile(2i+2) A1 -> buf0
        LDA(1, 0); LDB0(1);
        stage_half(AsS + 8192, Aap + 131072 + kc + 128, w, lane);
        BAR(); PRIO1(); MMQ(0, 0, af, b0f); PRIO0(); BAR();
        // ph6: buf1 B-nh1; stage tile(2i+2) B0 -> buf0
        LDB1(1);
        stage_half(BsS, Bbp + kc + 128, w, lane);
        BAR(); PRIO1(); MMQ(0, 1, af, b1f); PRIO0(); BAR();
        // ph7: buf1 A-mh1; stage tile(2i+2) B1 -> buf0
        LDA(1, 4);
        stage_half(BsS + 8192, Bbp + 131072 + kc + 128, w, lane);
        BAR(); PRIO1(); MMQ(1, 1, af, b1f); PRIO0(); BAR();
        // ph8: stage tile(2i+3) A0 -> buf1; counted wait for tile(2i+2)
        stage_half(AsS + 16384, Aap + kc + 192, w, lane);
        VMC2();
        BAR(); PRIO1(); MMQ(1, 0, af, b0f); PRIO0(); BAR();
    }

    const float qscale = (mode == 0) ? C2 : 1.0f;
#pragma unroll
    for (int mf = 0; mf < 8; ++mf) {
        const int mb = m0 + wr * 128 + mf * 16 + quad * 4;
        const int b_ = mb >> 11, s = mb & 2047;
#pragma unroll
        for (int nf = 0; nf < 4; ++nf) {
            const int n = n0 + wc * 64 + nf * 16 + l15;
            const int h = n >> 6, d = n & 63;
            if (mode == 2) {
                unsigned int lo = (unsigned int)bf16_bits(__float2bfloat16(acc[mf][nf][0]))
                                | ((unsigned int)bf16_bits(__float2bfloat16(acc[mf][nf][1])) << 16);
                unsigned int hi = (unsigned int)bf16_bits(__float2bfloat16(acc[mf][nf][2]))
                                | ((unsigned int)bf16_bits(__float2bfloat16(acc[mf][nf][3])) << 16);
                uint2 pv; pv.x = lo; pv.y = hi;
                *(uint2*)&vtd[((b_ * H_ + h) * HD_ + d) * S_ + s] = pv;
            } else {
                bf16* __restrict__ dst = (mode == 0) ? qd : kd;
#pragma unroll
                for (int r = 0; r < 4; ++r)
                    dst[((b_ * H_ + h) * S_ + (s + r)) * HD_ + d] =
                        __float2bfloat16(acc[mf][nf][r] * qscale);
            }
        }
    }
}

// ---------------------------------------------------------------------------
// Output GEMM (m97-style 128x128): 256 blocks keeps all CUs busy at N=1024.
// ---------------------------------------------------------------------------
__global__ __launch_bounds__(256)
void gemm_out_f(const bf16* __restrict__ ctx, const bf16* __restrict__ wob,
                const float* __restrict__ bo, float* __restrict__ out)
{
    const int m0 = blockIdx.x * 128;
    const int n0 = blockIdx.y * 128;
    __shared__ bf16 As[128 * 32];
    __shared__ bf16 Bs[128 * 32];
    const int t    = threadIdx.x;
    const int lane = t & 63, w = t >> 6;
    const int wr = w >> 1, wc = w & 1;
    const int l15 = lane & 15, quad = lane >> 4;
    const int r16 = lane >> 2, c8 = (lane & 3) * 8;
    v4f acc[4][4] = {};

    const bf16* ga = &ctx[(m0 + w*16 + r16) * 1024 + c8];
    const bf16* gb = &wob[(n0 + w*16 + r16) * 1024 + c8];
    bf16* la0 = &As[w * 16 * 32];
    bf16* la1 = &As[(64 + w * 16) * 32];
    bf16* lb0 = &Bs[w * 16 * 32];
    bf16* lb1 = &Bs[(64 + w * 16) * 32];

    for (int k0 = 0; k0 < 1024; k0 += 32) {
        __syncthreads();
        GLDS16(ga + k0,             la0);
        GLDS16(ga + k0 + 64 * 1024, la1);
        GLDS16(gb + k0,             lb0);
        GLDS16(gb + k0 + 64 * 1024, lb1);
        __syncthreads();
        v8s a[4], b[4];
#pragma unroll
        for (int mt = 0; mt < 4; mt++) a[mt] = *(const v8s*)&As[(wr*64 + mt*16 + l15)*32 + quad*8];
#pragma unroll
        for (int nt = 0; nt < 4; nt++) b[nt] = *(const v8s*)&Bs[(wc*64 + nt*16 + l15)*32 + quad*8];
#pragma unroll
        for (int mt = 0; mt < 4; mt++)
#pragma unroll
            for (int nt = 0; nt < 4; nt++)
                acc[mt][nt] = __builtin_amdgcn_mfma_f32_16x16x32_bf16(a[mt], b[nt], acc[mt][nt], 0, 0, 0);
    }

#pragma unroll
    for (int mt = 0; mt < 4; mt++) {
        const int mb = m0 + wr*64 + mt*16 + quad*4;
#pragma unroll
        for (int nt = 0; nt < 4; nt++) {
            const int n = n0 + wc*64 + nt*16 + l15;
            const float bias = bo[n];
#pragma unroll
            for (int r = 0; r < 4; r++)
                out[(mb + r)*1024 + n] = acc[mt][nt][r] + bias;
        }
    }
}

// ---------------------------------------------------------------------------
// FALLBACK GEMMs (fp32 inputs, cvt fused in staging)
// ---------------------------------------------------------------------------
__global__ __launch_bounds__(256)
void gemm_qkv(const float* __restrict__ x, const float* __restrict__ Wq,
              const float* __restrict__ Wk, const float* __restrict__ Wv,
              bf16* __restrict__ qd, bf16* __restrict__ kd, bf16* __restrict__ vtd)
{
    const int mode = blockIdx.z;
    const float* __restrict__ W = (mode == 0) ? Wq : (mode == 1) ? Wk : Wv;
    const int m0 = blockIdx.x * 128;
    const int n0 = blockIdx.y * 128;
    __shared__ bf16 As[128 * 40];
    __shared__ bf16 Bs[128 * 40];
    const int t    = threadIdx.x;
    const int lane = t & 63, w = t >> 6;
    const int wr = w >> 1, wc = w & 1;
    const int l15 = lane & 15, quad = lane >> 4;
    const int srow = t >> 2, scol = (t & 3) * 8;
    v4f acc[4][4] = {};

    for (int k0 = 0; k0 < 1024; k0 += 32) {
        __syncthreads();
        {
            const float* pa = &x[(m0 + srow) * 1024 + k0 + scol];
            *(v8s*)&As[srow*40 + scol] = pack_bf16x8(*(const float4*)pa, *(const float4*)(pa + 4));
            const float* pa2 = pa + 64 * 1024;
            *(v8s*)&As[(srow+64)*40 + scol] = pack_bf16x8(*(const float4*)pa2, *(const float4*)(pa2 + 4));
            const float* pb = &W[(n0 + srow) * 1024 + k0 + scol];
            *(v8s*)&Bs[srow*40 + scol] = pack_bf16x8(*(const float4*)pb, *(const float4*)(pb + 4));
            const float* pb2 = pb + 64 * 1024;
            *(v8s*)&Bs[(srow+64)*40 + scol] = pack_bf16x8(*(const float4*)pb2, *(const float4*)(pb2 + 4));
        }
        __syncthreads();
        v8s a[4], b[4];
#pragma unroll
        for (int mt = 0; mt < 4; mt++) a[mt] = *(const v8s*)&As[(wr*64 + mt*16 + l15)*40 + quad*8];
#pragma unroll
        for (int nt = 0; nt < 4; nt++) b[nt] = *(const v8s*)&Bs[(wc*64 + nt*16 + l15)*40 + quad*8];
#pragma unroll
        for (int mt = 0; mt < 4; mt++)
#pragma unroll
            for (int nt = 0; nt < 4; nt++)
                acc[mt][nt] = __builtin_amdgcn_mfma_f32_16x16x32_bf16(a[mt], b[nt], acc[mt][nt], 0, 0, 0);
    }

    const float qscale = (mode == 0) ? C2 : 1.0f;
#pragma unroll
    for (int mt = 0; mt < 4; mt++) {
        const int mb = m0 + wr*64 + mt*16 + quad*4;
        const int b_ = mb >> 11, s = mb & 2047;
#pragma unroll
        for (int nt = 0; nt < 4; nt++) {
            const int n = n0 + wc*64 + nt*16 + l15;
            const int h = n >> 6, d = n & 63;
            if (mode == 2) {
                unsigned int lo = (unsigned int)bf16_bits(__float2bfloat16(acc[mt][nt][0]))
                                | ((unsigned int)bf16_bits(__float2bfloat16(acc[mt][nt][1])) << 16);
                unsigned int hi = (unsigned int)bf16_bits(__float2bfloat16(acc[mt][nt][2]))
                                | ((unsigned int)bf16_bits(__float2bfloat16(acc[mt][nt][3])) << 16);
                uint2 pv; pv.x = lo; pv.y = hi;
                *(uint2*)&vtd[((b_*H_ + h)*HD_ + d)*S_ + s] = pv;
            } else {
                bf16* __restrict__ dst = (mode == 0) ? qd : kd;
#pragma unroll
                for (int r = 0; r < 4; r++)
                    dst[((b_*H_ + h)*S_ + (s + r))*HD_ + d] = __float2bfloat16(acc[mt][nt][r] * qscale);
            }
        }
    }
}

__global__ __launch_bounds__(256)
void gemm_out(const bf16* __restrict__ ctx, const float* __restrict__ Wo,
              const float* __restrict__ bo, float* __restrict__ out)
{
    const int m0 = blockIdx.x * 128;
    const int n0 = blockIdx.y * 128;
    __shared__ bf16 As[128 * 40];
    __shared__ bf16 Bs[128 * 40];
    const int t    = threadIdx.x;
    const int lane = t & 63, w = t >> 6;
    const int wr = w >> 1, wc = w & 1;
    const int l15 = lane & 15, quad = lane >> 4;
    const int srow = t >> 2, scol = (t & 3) * 8;
    v4f acc[4][4] = {};

    for (int k0 = 0; k0 < 1024; k0 += 32) {
        __syncthreads();
        {
            *(v8s*)&As[srow*40 + scol]      = *(const v8s*)&ctx[(m0+srow)*1024 + k0 + scol];
            *(v8s*)&As[(srow+64)*40 + scol] = *(const v8s*)&ctx[(m0+srow+64)*1024 + k0 + scol];
            const float* pb = &Wo[(n0 + srow) * 1024 + k0 + scol];
            *(v8s*)&Bs[srow*40 + scol] = pack_bf16x8(*(const float4*)pb, *(const float4*)(pb + 4));
            const float* pb2 = pb + 64 * 1024;
            *(v8s*)&Bs[(srow+64)*40 + scol] = pack_bf16x8(*(const float4*)pb2, *(const float4*)(pb2 + 4));
        }
        __syncthreads();
        v8s a[4], b[4];
#pragma unroll
        for (int mt = 0; mt < 4; mt++) a[mt] = *(const v8s*)&As[(wr*64 + mt*16 + l15)*40 + quad*8];
#pragma unroll
        for (int nt = 0; nt < 4; nt++) b[nt] = *(const v8s*)&Bs[(wc*64 + nt*16 + l15)*40 + quad*8];
#pragma unroll
        for (int mt = 0; mt < 4; mt++)
#pragma unroll
            for (int nt = 0; nt < 4; nt++)
                acc[mt][nt] = __builtin_amdgcn_mfma_f32_16x16x32_bf16(a[mt], b[nt], acc[mt][nt], 0, 0, 0);
    }

#pragma unroll
    for (int mt = 0; mt < 4; mt++) {
        const int mb = m0 + wr*64 + mt*16 + quad*4;
#pragma unroll
        for (int nt = 0; nt < 4; nt++) {
            const int n = n0 + wc*64 + nt*16 + l15;
            const float bias = bo[n];
#pragma unroll
            for (int r = 0; r < 4; r++)
                out[(mb + r)*1024 + n] = acc[mt][nt][r] + bias;
        }
    }
}

// ---------------------------------------------------------------------------
// Causal flash attention (v7, best measured 62.3us):
//  * 512-thread blocks (8 waves), each block owns the q-tile PAIR (p, 15-p):
//    per-block work = (2p+2) + (32-2p) = 34 tile-units, constant -> every CU
//    gets exactly one uniform block (grid 32 bh x 8 pairs = 256), no tail.
//  * K fragments read DIRECTLY from global with one-tile register prefetch.
//  * Single barrier/tile (V staging only), fixed-offset exp2 softmax.
// ---------------------------------------------------------------------------
__global__ __launch_bounds__(512)
void flash_attn(const bf16* __restrict__ qd, const bf16* __restrict__ kd,
                const bf16* __restrict__ vtd, bf16* __restrict__ ctx)
{
    const int bh = blockIdx.x;            // 0..31 — same bh => same XCD
    const int p  = blockIdx.y;            // 0..7: this block owns q-tiles p and 15-p
    const int t = threadIdx.x;            // 0..511
    const int lane = t & 63, w = t >> 6;  // 8 waves
    const int l15 = lane & 15, quad = lane >> 4;
    const int side = w >> 2, wl = w & 3;  // side 0: tile p, side 1: tile 15-p
    const int q0 = (side ? (15 - p) : p) * 128;
    const int nT = 32 - 2 * p;            // loop count = longer side's tiles

    __shared__ bf16 Vs[2][64 * 72];
    __shared__ bf16 Pl[8][16 * 72];

    const int mrow0 = q0 + wl * 16;
    const int mrow1 = q0 + 64 + wl * 16;

    v8s qf[2][2];
#pragma unroll
    for (int mt = 0; mt < 2; mt++) {
        const bf16* qb_ = qd + (bh*S_ + (mt ? mrow1 : mrow0) + l15) * HD_;
        qf[mt][0] = *(const v8s*)(qb_ + quad*8);
        qf[mt][1] = *(const v8s*)(qb_ + 32 + quad*8);
    }

    v4f o[2][4] = {};
    float ps[2][4] = {};

    // V staging: one v8s per thread per tile (64 rows x 64 cols, 512 threads)
    const int rowlo = t >> 3, col8 = (t & 7) * 8;
    const bf16* vp = vtd + (bh*HD_ + rowlo)*S_ + col8;
    v8s pv = *(const v8s*)vp;

    // K fragments direct from global (coalesced), one-tile register prefetch
    const bf16* kbase = kd + (size_t)bh * S_ * HD_;
    v8s kf[4][2];
#pragma unroll
    for (int kt = 0; kt < 4; kt++) {
        const bf16* kp_ = kbase + (kt*16 + l15)*HD_ + quad*8;
        kf[kt][0] = *(const v8s*)kp_;
        kf[kt][1] = *(const v8s*)(kp_ + 32);
    }

    for (int it = 0; it < nT; ++it) {
        const int c0 = it * 64;
        bf16* Vb = &Vs[it & 1][0];
        *(v8s*)&Vb[rowlo*72 + col8] = pv;
        __syncthreads();
        vp += 64;
        pv = *(const v8s*)vp;             // prefetch next V tile (overrun stays in ws)

        const bool act  = (c0      <= mrow1 + 15);
        const bool nact = (c0 + 64 <= mrow1 + 15);
        v8s nkf[4][2];
        if (nact) {                       // issue next K-tile loads early (hide L2 latency)
#pragma unroll
            for (int kt = 0; kt < 4; kt++) {
                const bf16* kp_ = kbase + (c0 + 64 + kt*16 + l15)*HD_ + quad*8;
                nkf[kt][0] = *(const v8s*)kp_;
                nkf[kt][1] = *(const v8s*)(kp_ + 32);
            }
        }

        if (act) {
            v8s vf[4][2];
#pragma unroll
            for (int dt = 0; dt < 4; dt++) {
                vf[dt][0] = *(const v8s*)&Vb[(dt*16 + l15)*72 + quad*8];
                vf[dt][1] = *(const v8s*)&Vb[(dt*16 + l15)*72 + 32 + quad*8];
            }

#pragma unroll
            for (int mt = 0; mt < 2; mt++) {
                const int mr = mt ? mrow1 : mrow0;
                if (c0 > mr + 15) continue;
                v4f sc[4] = {};
#pragma unroll
                for (int kt = 0; kt < 4; kt++) {
                    sc[kt] = __builtin_amdgcn_mfma_f32_16x16x32_bf16(qf[mt][0], kf[kt][0], sc[kt], 0, 0, 0);
                    sc[kt] = __builtin_amdgcn_mfma_f32_16x16x32_bf16(qf[mt][1], kf[kt][1], sc[kt], 0, 0, 0);
                }
                const bool full = (c0 + 63 <= mr);
#pragma unroll
                for (int r = 0; r < 4; r++) {
                    const int qg = mr + quad*4 + r;
#pragma unroll
                    for (int kt = 0; kt < 4; kt++) {
                        float s = sc[kt][r];
                        if (!full) {
                            const int kg = c0 + kt*16 + l15;
                            s = (kg <= qg) ? s : NEG_BIG;
                        }
                        const float pp = EXP2F(s);
                        sc[kt][r] = pp;
                        ps[mt][r] += pp;
                    }
                }
                bf16* pw = &Pl[w][0];
#pragma unroll
                for (int kt = 0; kt < 4; kt++)
#pragma unroll
                    for (int r = 0; r < 4; r++)
                        pw[(quad*4 + r)*72 + kt*16 + l15] = __float2bfloat16(sc[kt][r]);
                v8s pf0 = *(const v8s*)&pw[l15*72 + quad*8];
                v8s pf1 = *(const v8s*)&pw[l15*72 + 32 + quad*8];
#pragma unroll
                for (int dt = 0; dt < 4; dt++) {
                    o[mt][dt] = __builtin_amdgcn_mfma_f32_16x16x32_bf16(pf0, vf[dt][0], o[mt][dt], 0, 0, 0);
                    o[mt][dt] = __builtin_amdgcn_mfma_f32_16x16x32_bf16(pf1, vf[dt][1], o[mt][dt], 0, 0, 0);
                }
            }
        }
        if (nact) {
#pragma unroll
            for (int kt = 0; kt < 4; kt++) { kf[kt][0] = nkf[kt][0]; kf[kt][1] = nkf[kt][1]; }
        }
    }

    const int b_ = bh >> 4, h = bh & 15;
#pragma unroll
    for (int mt = 0; mt < 2; mt++) {
        const int mr = mt ? mrow1 : mrow0;
#pragma unroll
        for (int r = 0; r < 4; r++) {
            float l = ps[mt][r];
#pragma unroll
            for (int off = 1; off < 16; off <<= 1) l += __shfl_xor(l, off);
            const float linv = 1.0f / l;
            const int qg = mr + quad*4 + r;
#pragma unroll
            for (int dt = 0; dt < 4; dt++)
                ctx[(b_*S_ + qg)*D_ + h*HD_ + dt*16 + l15] = __float2bfloat16(o[mt][dt][r] * linv);
        }
    }
}

extern "C" void kernel_launch(void* const* d_in, const int* in_sizes, int n_in,
                              void* d_out, int out_size, void* d_ws, size_t ws_size,
                              hipStream_t stream) {
    const float* x  = (const float*)d_in[0];
    const float* Wq = (const float*)d_in[1];
    const float* Wk = (const float*)d_in[2];
    const float* Wv = (const float*)d_in[3];
    const float* Wo = (const float*)d_in[4];
    const float* bo = (const float*)d_in[5];
    float* out = (float*)d_out;

    const size_t SEG = (size_t)2 * H_ * S_ * HD_;      // 4 Mi bf16 elems = 8 MB
    bf16* qd  = (bf16*)d_ws;
    bf16* kd  = qd  + SEG;
    bf16* vtd = kd  + SEG;
    bf16* xc  = vtd + SEG;                             // x-bf16, later ctx
    bf16* wqb = xc + SEG;
    bf16* wkb = wqb + 1024 * 1024;
    bf16* wvb = wkb + 1024 * 1024;
    bf16* wob = wvb + 1024 * 1024;

    const size_t need_fast = (4 * SEG + 4 * 1024 * 1024) * sizeof(bf16);   // 40 MB

    if (ws_size >= need_fast) {
        cvt_bf16<<<dim3(2048, 5), 256, 0, stream>>>(x, Wq, Wk, Wv, Wo,
                                                    xc, wqb, wkb, wvb, wob);
        gemm_qkv_8p<<<dim3(16, 4, 3), 512, 0, stream>>>(xc, wqb, wkb, wvb, qd, kd, vtd);
        flash_attn<<<dim3(32, 8), 512, 0, stream>>>(qd, kd, vtd, xc);   // xc = ctx
        gemm_out_f<<<dim3(32, 8), 256, 0, stream>>>(xc, wob, bo, out);
    } else {
        gemm_qkv<<<dim3(32, 8, 3), 256, 0, stream>>>(x, Wq, Wk, Wv, qd, kd, vtd);
        flash_attn<<<dim3(32, 8), 512, 0, stream>>>(qd, kd, vtd, xc);
        gemm_out<<<dim3(32, 8), 256, 0, stream>>>(xc, Wo, bo, out);
    }
}

// Round 5
// 201.780 us; speedup vs baseline: 1.1053x; 1.0486x over previous
//
#include <hip/hip_runtime.h>
#include <hip/hip_bf16.h>

typedef __hip_bfloat16 bf16;
typedef short v8s __attribute__((ext_vector_type(8)));
typedef float v4f __attribute__((ext_vector_type(4)));

#define S_ 2048
#define D_ 1024
#define H_ 16
#define HD_ 64

#define EXP2F(x) __builtin_amdgcn_exp2f(x)   /* v_exp_f32: 2^x on gfx950 */
#define NEG_BIG (-1.0e30f)
#define C2 0.1803368801111244f   /* (1/sqrt(64)) * log2(e), folded into Q */

#define GLDS16(g, l) __builtin_amdgcn_global_load_lds(                        \
    (const __attribute__((address_space(1))) unsigned int*)(g),               \
    (__attribute__((address_space(3))) unsigned int*)(l), 16, 0, 0)

static __device__ __forceinline__ unsigned short bf16_bits(bf16 h) {
    union { bf16 h; unsigned short u; } c; c.h = h; return c.u;
}

static __device__ __forceinline__ v8s pack_bf16x8(const float4 a, const float4 b) {
    union { v8s v; unsigned short u[8]; } r;
    r.u[0] = bf16_bits(__float2bfloat16(a.x));
    r.u[1] = bf16_bits(__float2bfloat16(a.y));
    r.u[2] = bf16_bits(__float2bfloat16(a.z));
    r.u[3] = bf16_bits(__float2bfloat16(a.w));
    r.u[4] = bf16_bits(__float2bfloat16(b.x));
    r.u[5] = bf16_bits(__float2bfloat16(b.y));
    r.u[6] = bf16_bits(__float2bfloat16(b.z));
    r.u[7] = bf16_bits(__float2bfloat16(b.w));
    return r.v;
}

// ---------------------------------------------------------------------------
// fp32 -> bf16 conversion pre-pass
// ---------------------------------------------------------------------------
__global__ __launch_bounds__(256)
void cvt_bf16(const float* __restrict__ x,  const float* __restrict__ wq,
              const float* __restrict__ wk, const float* __restrict__ wv,
              const float* __restrict__ wo,
              bf16* __restrict__ xb,  bf16* __restrict__ wqb,
              bf16* __restrict__ wkb, bf16* __restrict__ wvb,
              bf16* __restrict__ wob)
{
    const int seg = blockIdx.y;
    const float* src; bf16* dst; int n;
    switch (seg) {
        case 0: src = x;  dst = xb;  n = 4096 * 1024; break;
        case 1: src = wq; dst = wqb; n = 1024 * 1024; break;
        case 2: src = wk; dst = wkb; n = 1024 * 1024; break;
        case 3: src = wv; dst = wvb; n = 1024 * 1024; break;
        default:src = wo; dst = wob; n = 1024 * 1024; break;
    }
    const int idx = (blockIdx.x * 256 + threadIdx.x) * 8;
    if (idx >= n) return;
    *(v8s*)&dst[idx] = pack_bf16x8(*(const float4*)&src[idx],
                                   *(const float4*)&src[idx + 4]);
}

// ---------------------------------------------------------------------------
// QKV GEMM, 256x256 8-phase schedule (T3+T4+T5) + T2 XOR-swizzled LDS.
// Schedule/waits identical to the round-3 verified version; only the LDS
// layout changed (rule 21: BOTH-sides-or-neither):
//  * global_load_lds dest stays LINEAR; the SOURCE lane->element map is
//    inverse-swizzled: lane fetches col-slot (c ^ row&7) of its 128B row
//    (pure permutation within one cache line -> zero coalescing loss).
//  * ds_read addresses apply the same involution: slot ^= (row & 7).
//  Effect: fragment reads go from 16-way bank conflict (row stride 128B,
//  fixed 16B col slot) to conflict-free (banks 4*(q ^ r7) spread).
// ---------------------------------------------------------------------------
static __device__ __forceinline__ void stage_half(bf16* ldsbase, const bf16* gbase,
                                                  int w, int l) {
    const int r = l >> 3, c = ((l & 7) ^ r) * 8;  // T2 inverse-swizzled source
    GLDS16(gbase + (size_t)((2 * w + 0) * 8 + r) * 1024 + c, ldsbase + (2 * w + 0) * 512);
    GLDS16(gbase + (size_t)((2 * w + 1) * 8 + r) * 1024 + c, ldsbase + (2 * w + 1) * 512);
}

#define MF16(a, b, c) __builtin_amdgcn_mfma_f32_16x16x32_bf16(a, b, c, 0, 0, 0)

#define LDA(buf, mf0) { _Pragma("unroll") for (int m_ = 0; m_ < 4; ++m_) {          \
    af[m_][0] = *(const v8s*)&AsS[(buf)*16384 + abase + ((mf0) + m_)*1024 + sw0];   \
    af[m_][1] = *(const v8s*)&AsS[(buf)*16384 + abase + ((mf0) + m_)*1024 + sw1]; } }
#define LDB0(buf) { _Pragma("unroll") for (int n_ = 0; n_ < 2; ++n_) {              \
    b0f[n_][0] = *(const v8s*)&BsS[(buf)*16384 + bbase + n_*1024 + sw0];            \
    b0f[n_][1] = *(const v8s*)&BsS[(buf)*16384 + bbase + n_*1024 + sw1]; } }
#define LDB1(buf) { _Pragma("unroll") for (int n_ = 0; n_ < 2; ++n_) {              \
    b1f[n_][0] = *(const v8s*)&BsS[(buf)*16384 + bbase + (2 + n_)*1024 + sw0];      \
    b1f[n_][1] = *(const v8s*)&BsS[(buf)*16384 + bbase + (2 + n_)*1024 + sw1]; } }
#define MMQ(MH, NH, AF, BF) { _Pragma("unroll") for (int m_ = 0; m_ < 4; ++m_)      \
    _Pragma("unroll") for (int n_ = 0; n_ < 2; ++n_) {                              \
      acc[(MH)*4 + m_][(NH)*2 + n_] =                                               \
        MF16(AF[m_][0], BF[n_][0], acc[(MH)*4 + m_][(NH)*2 + n_]);                  \
      acc[(MH)*4 + m_][(NH)*2 + n_] =                                               \
        MF16(AF[m_][1], BF[n_][1], acc[(MH)*4 + m_][(NH)*2 + n_]); } }
#define BAR() __builtin_amdgcn_s_barrier()
#define VMC2() asm volatile("s_waitcnt vmcnt(2)" ::: "memory")
#define PRIO1() __builtin_amdgcn_s_setprio(1)
#define PRIO0() __builtin_amdgcn_s_setprio(0)

__global__ __launch_bounds__(512, 2)
void gemm_qkv_8p(const bf16* __restrict__ xb, const bf16* __restrict__ wqb,
                 const bf16* __restrict__ wkb, const bf16* __restrict__ wvb,
                 bf16* __restrict__ qd, bf16* __restrict__ kd, bf16* __restrict__ vtd)
{
    __shared__ bf16 AsS[2 * 16384];          // [buf][half 128][64]
    __shared__ bf16 BsS[2 * 16384];
    const int mode = blockIdx.z;
    const bf16* __restrict__ W = (mode == 0) ? wqb : (mode == 1) ? wkb : wvb;
    const int m0 = blockIdx.x * 256;
    const int n0 = blockIdx.y * 256;
    const int t = threadIdx.x;
    const int lane = t & 63, w = t >> 6;
    const int wr = w >> 2, wc = w & 3;       // 2M x 4N waves
    const int l15 = lane & 15, quad = lane >> 4;
    const int sw0 = (quad ^ (l15 & 7)) * 8;          // T2 swizzled col-slots
    const int sw1 = ((quad + 4) ^ (l15 & 7)) * 8;
    const int abase = wr * 8192 + l15 * 64;
    const int bbase = (wc >> 1) * 8192 + (wc & 1) * 4096 + l15 * 64;
    const bf16* Aap = xb + (size_t)m0 * 1024;
    const bf16* Bbp = W + (size_t)n0 * 1024;

    v4f acc[8][4] = {};
    v8s af[4][2], b0f[2][2], b1f[2][2];

    // prologue: tile0 (buf0, 4 halves) + tile1 A0 (buf1); keep tile1-A0 in flight
    stage_half(AsS,          Aap,          w, lane);
    stage_half(AsS + 8192,   Aap + 131072, w, lane);
    stage_half(BsS,          Bbp,          w, lane);
    stage_half(BsS + 8192,   Bbp + 131072, w, lane);
    stage_half(AsS + 16384,  Aap + 64,     w, lane);
    VMC2();
    BAR();

    for (int i = 0; i < 8; ++i) {
        const int kc = i * 128;
        // ph1: buf0 A-mh0 + B-nh0; stage tile(2i+1) A1 -> buf1
        LDA(0, 0); LDB0(0);
        stage_half(AsS + 16384 + 8192, Aap + 131072 + kc + 64, w, lane);
        BAR(); PRIO1(); MMQ(0, 0, af, b0f); PRIO0(); BAR();
        // ph2: buf0 B-nh1; stage tile(2i+1) B0 -> buf1
        LDB1(0);
        stage_half(BsS + 16384, Bbp + kc + 64, w, lane);
        BAR(); PRIO1(); MMQ(0, 1, af, b1f); PRIO0(); BAR();
        // ph3: buf0 A-mh1; stage tile(2i+1) B1 -> buf1
        LDA(0, 4);
        stage_half(BsS + 16384 + 8192, Bbp + 131072 + kc + 64, w, lane);
        BAR(); PRIO1(); MMQ(1, 1, af, b1f); PRIO0(); BAR();
        // ph4: stage tile(2i+2) A0 -> buf0; counted wait for tile(2i+1)
        stage_half(AsS, Aap + kc + 128, w, lane);
        VMC2();
        BAR(); PRIO1(); MMQ(1, 0, af, b0f); PRIO0(); BAR();
        // ph5: buf1 A-mh0 + B-nh0; stage tile(2i+2) A1 -> buf0
        LDA(1, 0); LDB0(1);
        stage_half(AsS + 8192, Aap + 131072 + kc + 128, w, lane);
        BAR(); PRIO1(); MMQ(0, 0, af, b0f); PRIO0(); BAR();
        // ph6: buf1 B-nh1; stage tile(2i+2) B0 -> buf0
        LDB1(1);
        stage_half(BsS, Bbp + kc + 128, w, lane);
        BAR(); PRIO1(); MMQ(0, 1, af, b1f); PRIO0(); BAR();
        // ph7: buf1 A-mh1; stage tile(2i+2) B1 -> buf0
        LDA(1, 4);
        stage_half(BsS + 8192, Bbp + 131072 + kc + 128, w, lane);
        BAR(); PRIO1(); MMQ(1, 1, af, b1f); PRIO0(); BAR();
        // ph8: stage tile(2i+3) A0 -> buf1; counted wait for tile(2i+2)
        stage_half(AsS + 16384, Aap + kc + 192, w, lane);
        VMC2();
        BAR(); PRIO1(); MMQ(1, 0, af, b0f); PRIO0(); BAR();
    }

    const float qscale = (mode == 0) ? C2 : 1.0f;
#pragma unroll
    for (int mf = 0; mf < 8; ++mf) {
        const int mb = m0 + wr * 128 + mf * 16 + quad * 4;
        const int b_ = mb >> 11, s = mb & 2047;
#pragma unroll
        for (int nf = 0; nf < 4; ++nf) {
            const int n = n0 + wc * 64 + nf * 16 + l15;
            const int h = n >> 6, d = n & 63;
            if (mode == 2) {
                unsigned int lo = (unsigned int)bf16_bits(__float2bfloat16(acc[mf][nf][0]))
                                | ((unsigned int)bf16_bits(__float2bfloat16(acc[mf][nf][1])) << 16);
                unsigned int hi = (unsigned int)bf16_bits(__float2bfloat16(acc[mf][nf][2]))
                                | ((unsigned int)bf16_bits(__float2bfloat16(acc[mf][nf][3])) << 16);
                uint2 pv; pv.x = lo; pv.y = hi;
                *(uint2*)&vtd[((b_ * H_ + h) * HD_ + d) * S_ + s] = pv;
            } else {
                bf16* __restrict__ dst = (mode == 0) ? qd : kd;
#pragma unroll
                for (int r = 0; r < 4; ++r)
                    dst[((b_ * H_ + h) * S_ + (s + r)) * HD_ + d] =
                        __float2bfloat16(acc[mf][nf][r] * qscale);
            }
        }
    }
}

// ---------------------------------------------------------------------------
// Output GEMM (m97-style 128x128): 256 blocks keeps all CUs busy at N=1024.
// ---------------------------------------------------------------------------
__global__ __launch_bounds__(256)
void gemm_out_f(const bf16* __restrict__ ctx, const bf16* __restrict__ wob,
                const float* __restrict__ bo, float* __restrict__ out)
{
    const int m0 = blockIdx.x * 128;
    const int n0 = blockIdx.y * 128;
    __shared__ bf16 As[128 * 32];
    __shared__ bf16 Bs[128 * 32];
    const int t    = threadIdx.x;
    const int lane = t & 63, w = t >> 6;
    const int wr = w >> 1, wc = w & 1;
    const int l15 = lane & 15, quad = lane >> 4;
    const int r16 = lane >> 2, c8 = (lane & 3) * 8;
    v4f acc[4][4] = {};

    const bf16* ga = &ctx[(m0 + w*16 + r16) * 1024 + c8];
    const bf16* gb = &wob[(n0 + w*16 + r16) * 1024 + c8];
    bf16* la0 = &As[w * 16 * 32];
    bf16* la1 = &As[(64 + w * 16) * 32];
    bf16* lb0 = &Bs[w * 16 * 32];
    bf16* lb1 = &Bs[(64 + w * 16) * 32];

    for (int k0 = 0; k0 < 1024; k0 += 32) {
        __syncthreads();
        GLDS16(ga + k0,             la0);
        GLDS16(ga + k0 + 64 * 1024, la1);
        GLDS16(gb + k0,             lb0);
        GLDS16(gb + k0 + 64 * 1024, lb1);
        __syncthreads();
        v8s a[4], b[4];
#pragma unroll
        for (int mt = 0; mt < 4; mt++) a[mt] = *(const v8s*)&As[(wr*64 + mt*16 + l15)*32 + quad*8];
#pragma unroll
        for (int nt = 0; nt < 4; nt++) b[nt] = *(const v8s*)&Bs[(wc*64 + nt*16 + l15)*32 + quad*8];
#pragma unroll
        for (int mt = 0; mt < 4; mt++)
#pragma unroll
            for (int nt = 0; nt < 4; nt++)
                acc[mt][nt] = __builtin_amdgcn_mfma_f32_16x16x32_bf16(a[mt], b[nt], acc[mt][nt], 0, 0, 0);
    }

#pragma unroll
    for (int mt = 0; mt < 4; mt++) {
        const int mb = m0 + wr*64 + mt*16 + quad*4;
#pragma unroll
        for (int nt = 0; nt < 4; nt++) {
            const int n = n0 + wc*64 + nt*16 + l15;
            const float bias = bo[n];
#pragma unroll
            for (int r = 0; r < 4; r++)
                out[(mb + r)*1024 + n] = acc[mt][nt][r] + bias;
        }
    }
}

// ---------------------------------------------------------------------------
// FALLBACK GEMMs (fp32 inputs, cvt fused in staging)
// ---------------------------------------------------------------------------
__global__ __launch_bounds__(256)
void gemm_qkv(const float* __restrict__ x, const float* __restrict__ Wq,
              const float* __restrict__ Wk, const float* __restrict__ Wv,
              bf16* __restrict__ qd, bf16* __restrict__ kd, bf16* __restrict__ vtd)
{
    const int mode = blockIdx.z;
    const float* __restrict__ W = (mode == 0) ? Wq : (mode == 1) ? Wk : Wv;
    const int m0 = blockIdx.x * 128;
    const int n0 = blockIdx.y * 128;
    __shared__ bf16 As[128 * 40];
    __shared__ bf16 Bs[128 * 40];
    const int t    = threadIdx.x;
    const int lane = t & 63, w = t >> 6;
    const int wr = w >> 1, wc = w & 1;
    const int l15 = lane & 15, quad = lane >> 4;
    const int srow = t >> 2, scol = (t & 3) * 8;
    v4f acc[4][4] = {};

    for (int k0 = 0; k0 < 1024; k0 += 32) {
        __syncthreads();
        {
            const float* pa = &x[(m0 + srow) * 1024 + k0 + scol];
            *(v8s*)&As[srow*40 + scol] = pack_bf16x8(*(const float4*)pa, *(const float4*)(pa + 4));
            const float* pa2 = pa + 64 * 1024;
            *(v8s*)&As[(srow+64)*40 + scol] = pack_bf16x8(*(const float4*)pa2, *(const float4*)(pa2 + 4));
            const float* pb = &W[(n0 + srow) * 1024 + k0 + scol];
            *(v8s*)&Bs[srow*40 + scol] = pack_bf16x8(*(const float4*)pb, *(const float4*)(pb + 4));
            const float* pb2 = pb + 64 * 1024;
            *(v8s*)&Bs[(srow+64)*40 + scol] = pack_bf16x8(*(const float4*)pb2, *(const float4*)(pb2 + 4));
        }
        __syncthreads();
        v8s a[4], b[4];
#pragma unroll
        for (int mt = 0; mt < 4; mt++) a[mt] = *(const v8s*)&As[(wr*64 + mt*16 + l15)*40 + quad*8];
#pragma unroll
        for (int nt = 0; nt < 4; nt++) b[nt] = *(const v8s*)&Bs[(wc*64 + nt*16 + l15)*40 + quad*8];
#pragma unroll
        for (int mt = 0; mt < 4; mt++)
#pragma unroll
            for (int nt = 0; nt < 4; nt++)
                acc[mt][nt] = __builtin_amdgcn_mfma_f32_16x16x32_bf16(a[mt], b[nt], acc[mt][nt], 0, 0, 0);
    }

    const float qscale = (mode == 0) ? C2 : 1.0f;
#pragma unroll
    for (int mt = 0; mt < 4; mt++) {
        const int mb = m0 + wr*64 + mt*16 + quad*4;
        const int b_ = mb >> 11, s = mb & 2047;
#pragma unroll
        for (int nt = 0; nt < 4; nt++) {
            const int n = n0 + wc*64 + nt*16 + l15;
            const int h = n >> 6, d = n & 63;
            if (mode == 2) {
                unsigned int lo = (unsigned int)bf16_bits(__float2bfloat16(acc[mt][nt][0]))
                                | ((unsigned int)bf16_bits(__float2bfloat16(acc[mt][nt][1])) << 16);
                unsigned int hi = (unsigned int)bf16_bits(__float2bfloat16(acc[mt][nt][2]))
                                | ((unsigned int)bf16_bits(__float2bfloat16(acc[mt][nt][3])) << 16);
                uint2 pv; pv.x = lo; pv.y = hi;
                *(uint2*)&vtd[((b_*H_ + h)*HD_ + d)*S_ + s] = pv;
            } else {
                bf16* __restrict__ dst = (mode == 0) ? qd : kd;
#pragma unroll
                for (int r = 0; r < 4; r++)
                    dst[((b_*H_ + h)*S_ + (s + r))*HD_ + d] = __float2bfloat16(acc[mt][nt][r] * qscale);
            }
        }
    }
}

__global__ __launch_bounds__(256)
void gemm_out(const bf16* __restrict__ ctx, const float* __restrict__ Wo,
              const float* __restrict__ bo, float* __restrict__ out)
{
    const int m0 = blockIdx.x * 128;
    const int n0 = blockIdx.y * 128;
    __shared__ bf16 As[128 * 40];
    __shared__ bf16 Bs[128 * 40];
    const int t    = threadIdx.x;
    const int lane = t & 63, w = t >> 6;
    const int wr = w >> 1, wc = w & 1;
    const int l15 = lane & 15, quad = lane >> 4;
    const int srow = t >> 2, scol = (t & 3) * 8;
    v4f acc[4][4] = {};

    for (int k0 = 0; k0 < 1024; k0 += 32) {
        __syncthreads();
        {
            *(v8s*)&As[srow*40 + scol]      = *(const v8s*)&ctx[(m0+srow)*1024 + k0 + scol];
            *(v8s*)&As[(srow+64)*40 + scol] = *(const v8s*)&ctx[(m0+srow+64)*1024 + k0 + scol];
            const float* pb = &Wo[(n0 + srow) * 1024 + k0 + scol];
            *(v8s*)&Bs[srow*40 + scol] = pack_bf16x8(*(const float4*)pb, *(const float4*)(pb + 4));
            const float* pb2 = pb + 64 * 1024;
            *(v8s*)&Bs[(srow+64)*40 + scol] = pack_bf16x8(*(const float4*)pb2, *(const float4*)(pb2 + 4));
        }
        __syncthreads();
        v8s a[4], b[4];
#pragma unroll
        for (int mt = 0; mt < 4; mt++) a[mt] = *(const v8s*)&As[(wr*64 + mt*16 + l15)*40 + quad*8];
#pragma unroll
        for (int nt = 0; nt < 4; nt++) b[nt] = *(const v8s*)&Bs[(wc*64 + nt*16 + l15)*40 + quad*8];
#pragma unroll
        for (int mt = 0; mt < 4; mt++)
#pragma unroll
            for (int nt = 0; nt < 4; nt++)
                acc[mt][nt] = __builtin_amdgcn_mfma_f32_16x16x32_bf16(a[mt], b[nt], acc[mt][nt], 0, 0, 0);
    }

#pragma unroll
    for (int mt = 0; mt < 4; mt++) {
        const int mb = m0 + wr*64 + mt*16 + quad*4;
#pragma unroll
        for (int nt = 0; nt < 4; nt++) {
            const int n = n0 + wc*64 + nt*16 + l15;
            const float bias = bo[n];
#pragma unroll
            for (int r = 0; r < 4; r++)
                out[(mb + r)*1024 + n] = acc[mt][nt][r] + bias;
        }
    }
}

// ---------------------------------------------------------------------------
// Causal flash attention (v7 + T5 setprio, best measured 62.3us):
//  * 512-thread blocks (8 waves), each block owns the q-tile PAIR (p, 15-p):
//    per-block work = (2p+2) + (32-2p) = 34 tile-units, constant -> every CU
//    gets exactly one uniform block (grid 32 bh x 8 pairs = 256), no tail.
//  * K fragments read DIRECTLY from global with one-tile register prefetch.
//  * Single barrier/tile (V staging only), fixed-offset exp2 softmax.
//  * s_setprio(1) around QK/PV MFMA clusters (waves diverge within a tile).
// ---------------------------------------------------------------------------
__global__ __launch_bounds__(512)
void flash_attn(const bf16* __restrict__ qd, const bf16* __restrict__ kd,
                const bf16* __restrict__ vtd, bf16* __restrict__ ctx)
{
    const int bh = blockIdx.x;            // 0..31 — same bh => same XCD
    const int p  = blockIdx.y;            // 0..7: this block owns q-tiles p and 15-p
    const int t = threadIdx.x;            // 0..511
    const int lane = t & 63, w = t >> 6;  // 8 waves
    const int l15 = lane & 15, quad = lane >> 4;
    const int side = w >> 2, wl = w & 3;  // side 0: tile p, side 1: tile 15-p
    const int q0 = (side ? (15 - p) : p) * 128;
    const int nT = 32 - 2 * p;            // loop count = longer side's tiles

    __shared__ bf16 Vs[2][64 * 72];
    __shared__ bf16 Pl[8][16 * 72];

    const int mrow0 = q0 + wl * 16;
    const int mrow1 = q0 + 64 + wl * 16;

    v8s qf[2][2];
#pragma unroll
    for (int mt = 0; mt < 2; mt++) {
        const bf16* qb_ = qd + (bh*S_ + (mt ? mrow1 : mrow0) + l15) * HD_;
        qf[mt][0] = *(const v8s*)(qb_ + quad*8);
        qf[mt][1] = *(const v8s*)(qb_ + 32 + quad*8);
    }

    v4f o[2][4] = {};
    float ps[2][4] = {};

    // V staging: one v8s per thread per tile (64 rows x 64 cols, 512 threads)
    const int rowlo = t >> 3, col8 = (t & 7) * 8;
    const bf16* vp = vtd + (bh*HD_ + rowlo)*S_ + col8;
    v8s pv = *(const v8s*)vp;

    // K fragments direct from global (coalesced), one-tile register prefetch
    const bf16* kbase = kd + (size_t)bh * S_ * HD_;
    v8s kf[4][2];
#pragma unroll
    for (int kt = 0; kt < 4; kt++) {
        const bf16* kp_ = kbase + (kt*16 + l15)*HD_ + quad*8;
        kf[kt][0] = *(const v8s*)kp_;
        kf[kt][1] = *(const v8s*)(kp_ + 32);
    }

    for (int it = 0; it < nT; ++it) {
        const int c0 = it * 64;
        bf16* Vb = &Vs[it & 1][0];
        *(v8s*)&Vb[rowlo*72 + col8] = pv;
        __syncthreads();
        vp += 64;
        pv = *(const v8s*)vp;             // prefetch next V tile (overrun stays in ws)

        const bool act  = (c0      <= mrow1 + 15);
        const bool nact = (c0 + 64 <= mrow1 + 15);
        v8s nkf[4][2];
        if (nact) {                       // issue next K-tile loads early (hide L2 latency)
#pragma unroll
            for (int kt = 0; kt < 4; kt++) {
                const bf16* kp_ = kbase + (c0 + 64 + kt*16 + l15)*HD_ + quad*8;
                nkf[kt][0] = *(const v8s*)kp_;
                nkf[kt][1] = *(const v8s*)(kp_ + 32);
            }
        }

        if (act) {
            v8s vf[4][2];
#pragma unroll
            for (int dt = 0; dt < 4; dt++) {
                vf[dt][0] = *(const v8s*)&Vb[(dt*16 + l15)*72 + quad*8];
                vf[dt][1] = *(const v8s*)&Vb[(dt*16 + l15)*72 + 32 + quad*8];
            }

#pragma unroll
            for (int mt = 0; mt < 2; mt++) {
                const int mr = mt ? mrow1 : mrow0;
                if (c0 > mr + 15) continue;
                v4f sc[4] = {};
                __builtin_amdgcn_s_setprio(1);
#pragma unroll
                for (int kt = 0; kt < 4; kt++) {
                    sc[kt] = __builtin_amdgcn_mfma_f32_16x16x32_bf16(qf[mt][0], kf[kt][0], sc[kt], 0, 0, 0);
                    sc[kt] = __builtin_amdgcn_mfma_f32_16x16x32_bf16(qf[mt][1], kf[kt][1], sc[kt], 0, 0, 0);
                }
                __builtin_amdgcn_s_setprio(0);
                const bool full = (c0 + 63 <= mr);
#pragma unroll
                for (int r = 0; r < 4; r++) {
                    const int qg = mr + quad*4 + r;
#pragma unroll
                    for (int kt = 0; kt < 4; kt++) {
                        float s = sc[kt][r];
                        if (!full) {
                            const int kg = c0 + kt*16 + l15;
                            s = (kg <= qg) ? s : NEG_BIG;
                        }
                        const float pp = EXP2F(s);
                        sc[kt][r] = pp;
                        ps[mt][r] += pp;
                    }
                }
                bf16* pw = &Pl[w][0];
#pragma unroll
                for (int kt = 0; kt < 4; kt++)
#pragma unroll
                    for (int r = 0; r < 4; r++)
                        pw[(quad*4 + r)*72 + kt*16 + l15] = __float2bfloat16(sc[kt][r]);
                v8s pf0 = *(const v8s*)&pw[l15*72 + quad*8];
                v8s pf1 = *(const v8s*)&pw[l15*72 + 32 + quad*8];
                __builtin_amdgcn_s_setprio(1);
#pragma unroll
                for (int dt = 0; dt < 4; dt++) {
                    o[mt][dt] = __builtin_amdgcn_mfma_f32_16x16x32_bf16(pf0, vf[dt][0], o[mt][dt], 0, 0, 0);
                    o[mt][dt] = __builtin_amdgcn_mfma_f32_16x16x32_bf16(pf1, vf[dt][1], o[mt][dt], 0, 0, 0);
                }
                __builtin_amdgcn_s_setprio(0);
            }
        }
        if (nact) {
#pragma unroll
            for (int kt = 0; kt < 4; kt++) { kf[kt][0] = nkf[kt][0]; kf[kt][1] = nkf[kt][1]; }
        }
    }

    const int b_ = bh >> 4, h = bh & 15;
#pragma unroll
    for (int mt = 0; mt < 2; mt++) {
        const int mr = mt ? mrow1 : mrow0;
#pragma unroll
        for (int r = 0; r < 4; r++) {
            float l = ps[mt][r];
#pragma unroll
            for (int off = 1; off < 16; off <<= 1) l += __shfl_xor(l, off);
            const float linv = 1.0f / l;
            const int qg = mr + quad*4 + r;
#pragma unroll
            for (int dt = 0; dt < 4; dt++)
                ctx[(b_*S_ + qg)*D_ + h*HD_ + dt*16 + l15] = __float2bfloat16(o[mt][dt][r] * linv);
        }
    }
}

extern "C" void kernel_launch(void* const* d_in, const int* in_sizes, int n_in,
                              void* d_out, int out_size, void* d_ws, size_t ws_size,
                              hipStream_t stream) {
    const float* x  = (const float*)d_in[0];
    const float* Wq = (const float*)d_in[1];
    const float* Wk = (const float*)d_in[2];
    const float* Wv = (const float*)d_in[3];
    const float* Wo = (const float*)d_in[4];
    const float* bo = (const float*)d_in[5];
    float* out = (float*)d_out;

    const size_t SEG = (size_t)2 * H_ * S_ * HD_;      // 4 Mi bf16 elems = 8 MB
    bf16* qd  = (bf16*)d_ws;
    bf16* kd  = qd  + SEG;
    bf16* vtd = kd  + SEG;
    bf16* xc  = vtd + SEG;                             // x-bf16, later ctx
    bf16* wqb = xc + SEG;
    bf16* wkb = wqb + 1024 * 1024;
    bf16* wvb = wkb + 1024 * 1024;
    bf16* wob = wvb + 1024 * 1024;

    const size_t need_fast = (4 * SEG + 4 * 1024 * 1024) * sizeof(bf16);   // 40 MB

    if (ws_size >= need_fast) {
        cvt_bf16<<<dim3(2048, 5), 256, 0, stream>>>(x, Wq, Wk, Wv, Wo,
                                                    xc, wqb, wkb, wvb, wob);
        gemm_qkv_8p<<<dim3(16, 4, 3), 512, 0, stream>>>(xc, wqb, wkb, wvb, qd, kd, vtd);
        flash_attn<<<dim3(32, 8), 512, 0, stream>>>(qd, kd, vtd, xc);   // xc = ctx
        gemm_out_f<<<dim3(32, 8), 256, 0, stream>>>(xc, wob, bo, out);
    } else {
        gemm_qkv<<<dim3(32, 8, 3), 256, 0, stream>>>(x, Wq, Wk, Wv, qd, kd, vtd);
        flash_attn<<<dim3(32, 8), 512, 0, stream>>>(qd, kd, vtd, xc);
        gemm_out<<<dim3(32, 8), 256, 0, stream>>>(xc, Wo, bo, out);
    }
}

// Round 6
// 199.299 us; speedup vs baseline: 1.1190x; 1.0124x over previous
//
#include <hip/hip_runtime.h>
#include <hip/hip_bf16.h>

typedef __hip_bfloat16 bf16;
typedef short v8s __attribute__((ext_vector_type(8)));
typedef float v4f __attribute__((ext_vector_type(4)));

#define S_ 2048
#define D_ 1024
#define H_ 16
#define HD_ 64

#define EXP2F(x) __builtin_amdgcn_exp2f(x)   /* v_exp_f32: 2^x on gfx950 */
#define NEG_BIG (-1.0e30f)
#define C2 0.1803368801111244f   /* (1/sqrt(64)) * log2(e), folded into Q */

#define GLDS16(g, l) __builtin_amdgcn_global_load_lds(                        \
    (const __attribute__((address_space(1))) unsigned int*)(g),               \
    (__attribute__((address_space(3))) unsigned int*)(l), 16, 0, 0)

static __device__ __forceinline__ unsigned short bf16_bits(bf16 h) {
    union { bf16 h; unsigned short u; } c; c.h = h; return c.u;
}

static __device__ __forceinline__ v8s pack_bf16x8(const float4 a, const float4 b) {
    union { v8s v; unsigned short u[8]; } r;
    r.u[0] = bf16_bits(__float2bfloat16(a.x));
    r.u[1] = bf16_bits(__float2bfloat16(a.y));
    r.u[2] = bf16_bits(__float2bfloat16(a.z));
    r.u[3] = bf16_bits(__float2bfloat16(a.w));
    r.u[4] = bf16_bits(__float2bfloat16(b.x));
    r.u[5] = bf16_bits(__float2bfloat16(b.y));
    r.u[6] = bf16_bits(__float2bfloat16(b.z));
    r.u[7] = bf16_bits(__float2bfloat16(b.w));
    return r.v;
}

// ---------------------------------------------------------------------------
// fp32 -> bf16 conversion pre-pass
// ---------------------------------------------------------------------------
__global__ __launch_bounds__(256)
void cvt_bf16(const float* __restrict__ x,  const float* __restrict__ wq,
              const float* __restrict__ wk, const float* __restrict__ wv,
              const float* __restrict__ wo,
              bf16* __restrict__ xb,  bf16* __restrict__ wqb,
              bf16* __restrict__ wkb, bf16* __restrict__ wvb,
              bf16* __restrict__ wob)
{
    const int seg = blockIdx.y;
    const float* src; bf16* dst; int n;
    switch (seg) {
        case 0: src = x;  dst = xb;  n = 4096 * 1024; break;
        case 1: src = wq; dst = wqb; n = 1024 * 1024; break;
        case 2: src = wk; dst = wkb; n = 1024 * 1024; break;
        case 3: src = wv; dst = wvb; n = 1024 * 1024; break;
        default:src = wo; dst = wob; n = 1024 * 1024; break;
    }
    const int idx = (blockIdx.x * 256 + threadIdx.x) * 8;
    if (idx >= n) return;
    *(v8s*)&dst[idx] = pack_bf16x8(*(const float4*)&src[idx],
                                   *(const float4*)&src[idx + 4]);
}

// ---------------------------------------------------------------------------
// QKV GEMM, 256x256 8-phase schedule (T3+T4+T5) + T2 XOR-swizzled LDS.
// (Verified round 4: T2 on the 8-phase structure gave ~-11us vs linear LDS.)
// ---------------------------------------------------------------------------
static __device__ __forceinline__ void stage_half(bf16* ldsbase, const bf16* gbase,
                                                  int w, int l) {
    const int r = l >> 3, c = ((l & 7) ^ r) * 8;  // T2 inverse-swizzled source
    GLDS16(gbase + (size_t)((2 * w + 0) * 8 + r) * 1024 + c, ldsbase + (2 * w + 0) * 512);
    GLDS16(gbase + (size_t)((2 * w + 1) * 8 + r) * 1024 + c, ldsbase + (2 * w + 1) * 512);
}

#define MF16(a, b, c) __builtin_amdgcn_mfma_f32_16x16x32_bf16(a, b, c, 0, 0, 0)

#define LDA(buf, mf0) { _Pragma("unroll") for (int m_ = 0; m_ < 4; ++m_) {          \
    af[m_][0] = *(const v8s*)&AsS[(buf)*16384 + abase + ((mf0) + m_)*1024 + sw0];   \
    af[m_][1] = *(const v8s*)&AsS[(buf)*16384 + abase + ((mf0) + m_)*1024 + sw1]; } }
#define LDB0(buf) { _Pragma("unroll") for (int n_ = 0; n_ < 2; ++n_) {              \
    b0f[n_][0] = *(const v8s*)&BsS[(buf)*16384 + bbase + n_*1024 + sw0];            \
    b0f[n_][1] = *(const v8s*)&BsS[(buf)*16384 + bbase + n_*1024 + sw1]; } }
#define LDB1(buf) { _Pragma("unroll") for (int n_ = 0; n_ < 2; ++n_) {              \
    b1f[n_][0] = *(const v8s*)&BsS[(buf)*16384 + bbase + (2 + n_)*1024 + sw0];      \
    b1f[n_][1] = *(const v8s*)&BsS[(buf)*16384 + bbase + (2 + n_)*1024 + sw1]; } }
#define MMQ(MH, NH, AF, BF) { _Pragma("unroll") for (int m_ = 0; m_ < 4; ++m_)      \
    _Pragma("unroll") for (int n_ = 0; n_ < 2; ++n_) {                              \
      acc[(MH)*4 + m_][(NH)*2 + n_] =                                               \
        MF16(AF[m_][0], BF[n_][0], acc[(MH)*4 + m_][(NH)*2 + n_]);                  \
      acc[(MH)*4 + m_][(NH)*2 + n_] =                                               \
        MF16(AF[m_][1], BF[n_][1], acc[(MH)*4 + m_][(NH)*2 + n_]); } }
#define BAR() __builtin_amdgcn_s_barrier()
#define VMC2() asm volatile("s_waitcnt vmcnt(2)" ::: "memory")
#define PRIO1() __builtin_amdgcn_s_setprio(1)
#define PRIO0() __builtin_amdgcn_s_setprio(0)

__global__ __launch_bounds__(512, 2)
void gemm_qkv_8p(const bf16* __restrict__ xb, const bf16* __restrict__ wqb,
                 const bf16* __restrict__ wkb, const bf16* __restrict__ wvb,
                 bf16* __restrict__ qd, bf16* __restrict__ kd, bf16* __restrict__ vtd)
{
    __shared__ bf16 AsS[2 * 16384];          // [buf][half 128][64]
    __shared__ bf16 BsS[2 * 16384];
    const int mode = blockIdx.z;
    const bf16* __restrict__ W = (mode == 0) ? wqb : (mode == 1) ? wkb : wvb;
    const int m0 = blockIdx.x * 256;
    const int n0 = blockIdx.y * 256;
    const int t = threadIdx.x;
    const int lane = t & 63, w = t >> 6;
    const int wr = w >> 2, wc = w & 3;       // 2M x 4N waves
    const int l15 = lane & 15, quad = lane >> 4;
    const int sw0 = (quad ^ (l15 & 7)) * 8;          // T2 swizzled col-slots
    const int sw1 = ((quad + 4) ^ (l15 & 7)) * 8;
    const int abase = wr * 8192 + l15 * 64;
    const int bbase = (wc >> 1) * 8192 + (wc & 1) * 4096 + l15 * 64;
    const bf16* Aap = xb + (size_t)m0 * 1024;
    const bf16* Bbp = W + (size_t)n0 * 1024;

    v4f acc[8][4] = {};
    v8s af[4][2], b0f[2][2], b1f[2][2];

    // prologue: tile0 (buf0, 4 halves) + tile1 A0 (buf1); keep tile1-A0 in flight
    stage_half(AsS,          Aap,          w, lane);
    stage_half(AsS + 8192,   Aap + 131072, w, lane);
    stage_half(BsS,          Bbp,          w, lane);
    stage_half(BsS + 8192,   Bbp + 131072, w, lane);
    stage_half(AsS + 16384,  Aap + 64,     w, lane);
    VMC2();
    BAR();

    for (int i = 0; i < 8; ++i) {
        const int kc = i * 128;
        // ph1: buf0 A-mh0 + B-nh0; stage tile(2i+1) A1 -> buf1
        LDA(0, 0); LDB0(0);
        stage_half(AsS + 16384 + 8192, Aap + 131072 + kc + 64, w, lane);
        BAR(); PRIO1(); MMQ(0, 0, af, b0f); PRIO0(); BAR();
        // ph2: buf0 B-nh1; stage tile(2i+1) B0 -> buf1
        LDB1(0);
        stage_half(BsS + 16384, Bbp + kc + 64, w, lane);
        BAR(); PRIO1(); MMQ(0, 1, af, b1f); PRIO0(); BAR();
        // ph3: buf0 A-mh1; stage tile(2i+1) B1 -> buf1
        LDA(0, 4);
        stage_half(BsS + 16384 + 8192, Bbp + 131072 + kc + 64, w, lane);
        BAR(); PRIO1(); MMQ(1, 1, af, b1f); PRIO0(); BAR();
        // ph4: stage tile(2i+2) A0 -> buf0; counted wait for tile(2i+1)
        stage_half(AsS, Aap + kc + 128, w, lane);
        VMC2();
        BAR(); PRIO1(); MMQ(1, 0, af, b0f); PRIO0(); BAR();
        // ph5: buf1 A-mh0 + B-nh0; stage tile(2i+2) A1 -> buf0
        LDA(1, 0); LDB0(1);
        stage_half(AsS + 8192, Aap + 131072 + kc + 128, w, lane);
        BAR(); PRIO1(); MMQ(0, 0, af, b0f); PRIO0(); BAR();
        // ph6: buf1 B-nh1; stage tile(2i+2) B0 -> buf0
        LDB1(1);
        stage_half(BsS, Bbp + kc + 128, w, lane);
        BAR(); PRIO1(); MMQ(0, 1, af, b1f); PRIO0(); BAR();
        // ph7: buf1 A-mh1; stage tile(2i+2) B1 -> buf0
        LDA(1, 4);
        stage_half(BsS + 8192, Bbp + 131072 + kc + 128, w, lane);
        BAR(); PRIO1(); MMQ(1, 1, af, b1f); PRIO0(); BAR();
        // ph8: stage tile(2i+3) A0 -> buf1; counted wait for tile(2i+2)
        stage_half(AsS + 16384, Aap + kc + 192, w, lane);
        VMC2();
        BAR(); PRIO1(); MMQ(1, 0, af, b0f); PRIO0(); BAR();
    }

    const float qscale = (mode == 0) ? C2 : 1.0f;
#pragma unroll
    for (int mf = 0; mf < 8; ++mf) {
        const int mb = m0 + wr * 128 + mf * 16 + quad * 4;
        const int b_ = mb >> 11, s = mb & 2047;
#pragma unroll
        for (int nf = 0; nf < 4; ++nf) {
            const int n = n0 + wc * 64 + nf * 16 + l15;
            const int h = n >> 6, d = n & 63;
            if (mode == 2) {
                unsigned int lo = (unsigned int)bf16_bits(__float2bfloat16(acc[mf][nf][0]))
                                | ((unsigned int)bf16_bits(__float2bfloat16(acc[mf][nf][1])) << 16);
                unsigned int hi = (unsigned int)bf16_bits(__float2bfloat16(acc[mf][nf][2]))
                                | ((unsigned int)bf16_bits(__float2bfloat16(acc[mf][nf][3])) << 16);
                uint2 pv; pv.x = lo; pv.y = hi;
                *(uint2*)&vtd[((b_ * H_ + h) * HD_ + d) * S_ + s] = pv;
            } else {
                bf16* __restrict__ dst = (mode == 0) ? qd : kd;
#pragma unroll
                for (int r = 0; r < 4; ++r)
                    dst[((b_ * H_ + h) * S_ + (s + r)) * HD_ + d] =
                        __float2bfloat16(acc[mf][nf][r] * qscale);
            }
        }
    }
}

// ---------------------------------------------------------------------------
// Output GEMM (m97-style 128x128): 256 blocks keeps all CUs busy at N=1024.
// ---------------------------------------------------------------------------
__global__ __launch_bounds__(256)
void gemm_out_f(const bf16* __restrict__ ctx, const bf16* __restrict__ wob,
                const float* __restrict__ bo, float* __restrict__ out)
{
    const int m0 = blockIdx.x * 128;
    const int n0 = blockIdx.y * 128;
    __shared__ bf16 As[128 * 32];
    __shared__ bf16 Bs[128 * 32];
    const int t    = threadIdx.x;
    const int lane = t & 63, w = t >> 6;
    const int wr = w >> 1, wc = w & 1;
    const int l15 = lane & 15, quad = lane >> 4;
    const int r16 = lane >> 2, c8 = (lane & 3) * 8;
    v4f acc[4][4] = {};

    const bf16* ga = &ctx[(m0 + w*16 + r16) * 1024 + c8];
    const bf16* gb = &wob[(n0 + w*16 + r16) * 1024 + c8];
    bf16* la0 = &As[w * 16 * 32];
    bf16* la1 = &As[(64 + w * 16) * 32];
    bf16* lb0 = &Bs[w * 16 * 32];
    bf16* lb1 = &Bs[(64 + w * 16) * 32];

    for (int k0 = 0; k0 < 1024; k0 += 32) {
        __syncthreads();
        GLDS16(ga + k0,             la0);
        GLDS16(ga + k0 + 64 * 1024, la1);
        GLDS16(gb + k0,             lb0);
        GLDS16(gb + k0 + 64 * 1024, lb1);
        __syncthreads();
        v8s a[4], b[4];
#pragma unroll
        for (int mt = 0; mt < 4; mt++) a[mt] = *(const v8s*)&As[(wr*64 + mt*16 + l15)*32 + quad*8];
#pragma unroll
        for (int nt = 0; nt < 4; nt++) b[nt] = *(const v8s*)&Bs[(wc*64 + nt*16 + l15)*32 + quad*8];
#pragma unroll
        for (int mt = 0; mt < 4; mt++)
#pragma unroll
            for (int nt = 0; nt < 4; nt++)
                acc[mt][nt] = __builtin_amdgcn_mfma_f32_16x16x32_bf16(a[mt], b[nt], acc[mt][nt], 0, 0, 0);
    }

#pragma unroll
    for (int mt = 0; mt < 4; mt++) {
        const int mb = m0 + wr*64 + mt*16 + quad*4;
#pragma unroll
        for (int nt = 0; nt < 4; nt++) {
            const int n = n0 + wc*64 + nt*16 + l15;
            const float bias = bo[n];
#pragma unroll
            for (int r = 0; r < 4; r++)
                out[(mb + r)*1024 + n] = acc[mt][nt][r] + bias;
        }
    }
}

// ---------------------------------------------------------------------------
// FALLBACK GEMMs (fp32 inputs, cvt fused in staging)
// ---------------------------------------------------------------------------
__global__ __launch_bounds__(256)
void gemm_qkv(const float* __restrict__ x, const float* __restrict__ Wq,
              const float* __restrict__ Wk, const float* __restrict__ Wv,
              bf16* __restrict__ qd, bf16* __restrict__ kd, bf16* __restrict__ vtd)
{
    const int mode = blockIdx.z;
    const float* __restrict__ W = (mode == 0) ? Wq : (mode == 1) ? Wk : Wv;
    const int m0 = blockIdx.x * 128;
    const int n0 = blockIdx.y * 128;
    __shared__ bf16 As[128 * 40];
    __shared__ bf16 Bs[128 * 40];
    const int t    = threadIdx.x;
    const int lane = t & 63, w = t >> 6;
    const int wr = w >> 1, wc = w & 1;
    const int l15 = lane & 15, quad = lane >> 4;
    const int srow = t >> 2, scol = (t & 3) * 8;
    v4f acc[4][4] = {};

    for (int k0 = 0; k0 < 1024; k0 += 32) {
        __syncthreads();
        {
            const float* pa = &x[(m0 + srow) * 1024 + k0 + scol];
            *(v8s*)&As[srow*40 + scol] = pack_bf16x8(*(const float4*)pa, *(const float4*)(pa + 4));
            const float* pa2 = pa + 64 * 1024;
            *(v8s*)&As[(srow+64)*40 + scol] = pack_bf16x8(*(const float4*)pa2, *(const float4*)(pa2 + 4));
            const float* pb = &W[(n0 + srow) * 1024 + k0 + scol];
            *(v8s*)&Bs[srow*40 + scol] = pack_bf16x8(*(const float4*)pb, *(const float4*)(pb + 4));
            const float* pb2 = pb + 64 * 1024;
            *(v8s*)&Bs[(srow+64)*40 + scol] = pack_bf16x8(*(const float4*)pb2, *(const float4*)(pb2 + 4));
        }
        __syncthreads();
        v8s a[4], b[4];
#pragma unroll
        for (int mt = 0; mt < 4; mt++) a[mt] = *(const v8s*)&As[(wr*64 + mt*16 + l15)*40 + quad*8];
#pragma unroll
        for (int nt = 0; nt < 4; nt++) b[nt] = *(const v8s*)&Bs[(wc*64 + nt*16 + l15)*40 + quad*8];
#pragma unroll
        for (int mt = 0; mt < 4; mt++)
#pragma unroll
            for (int nt = 0; nt < 4; nt++)
                acc[mt][nt] = __builtin_amdgcn_mfma_f32_16x16x32_bf16(a[mt], b[nt], acc[mt][nt], 0, 0, 0);
    }

    const float qscale = (mode == 0) ? C2 : 1.0f;
#pragma unroll
    for (int mt = 0; mt < 4; mt++) {
        const int mb = m0 + wr*64 + mt*16 + quad*4;
        const int b_ = mb >> 11, s = mb & 2047;
#pragma unroll
        for (int nt = 0; nt < 4; nt++) {
            const int n = n0 + wc*64 + nt*16 + l15;
            const int h = n >> 6, d = n & 63;
            if (mode == 2) {
                unsigned int lo = (unsigned int)bf16_bits(__float2bfloat16(acc[mt][nt][0]))
                                | ((unsigned int)bf16_bits(__float2bfloat16(acc[mt][nt][1])) << 16);
                unsigned int hi = (unsigned int)bf16_bits(__float2bfloat16(acc[mt][nt][2]))
                                | ((unsigned int)bf16_bits(__float2bfloat16(acc[mt][nt][3])) << 16);
                uint2 pv; pv.x = lo; pv.y = hi;
                *(uint2*)&vtd[((b_*H_ + h)*HD_ + d)*S_ + s] = pv;
            } else {
                bf16* __restrict__ dst = (mode == 0) ? qd : kd;
#pragma unroll
                for (int r = 0; r < 4; r++)
                    dst[((b_*H_ + h)*S_ + (s + r))*HD_ + d] = __float2bfloat16(acc[mt][nt][r] * qscale);
            }
        }
    }
}

__global__ __launch_bounds__(256)
void gemm_out(const bf16* __restrict__ ctx, const float* __restrict__ Wo,
              const float* __restrict__ bo, float* __restrict__ out)
{
    const int m0 = blockIdx.x * 128;
    const int n0 = blockIdx.y * 128;
    __shared__ bf16 As[128 * 40];
    __shared__ bf16 Bs[128 * 40];
    const int t    = threadIdx.x;
    const int lane = t & 63, w = t >> 6;
    const int wr = w >> 1, wc = w & 1;
    const int l15 = lane & 15, quad = lane >> 4;
    const int srow = t >> 2, scol = (t & 3) * 8;
    v4f acc[4][4] = {};

    for (int k0 = 0; k0 < 1024; k0 += 32) {
        __syncthreads();
        {
            *(v8s*)&As[srow*40 + scol]      = *(const v8s*)&ctx[(m0+srow)*1024 + k0 + scol];
            *(v8s*)&As[(srow+64)*40 + scol] = *(const v8s*)&ctx[(m0+srow+64)*1024 + k0 + scol];
            const float* pb = &Wo[(n0 + srow) * 1024 + k0 + scol];
            *(v8s*)&Bs[srow*40 + scol] = pack_bf16x8(*(const float4*)pb, *(const float4*)(pb + 4));
            const float* pb2 = pb + 64 * 1024;
            *(v8s*)&Bs[(srow+64)*40 + scol] = pack_bf16x8(*(const float4*)pb2, *(const float4*)(pb2 + 4));
        }
        __syncthreads();
        v8s a[4], b[4];
#pragma unroll
        for (int mt = 0; mt < 4; mt++) a[mt] = *(const v8s*)&As[(wr*64 + mt*16 + l15)*40 + quad*8];
#pragma unroll
        for (int nt = 0; nt < 4; nt++) b[nt] = *(const v8s*)&Bs[(wc*64 + nt*16 + l15)*40 + quad*8];
#pragma unroll
        for (int mt = 0; mt < 4; mt++)
#pragma unroll
            for (int nt = 0; nt < 4; nt++)
                acc[mt][nt] = __builtin_amdgcn_mfma_f32_16x16x32_bf16(a[mt], b[nt], acc[mt][nt], 0, 0, 0);
    }

#pragma unroll
    for (int mt = 0; mt < 4; mt++) {
        const int mb = m0 + wr*64 + mt*16 + quad*4;
#pragma unroll
        for (int nt = 0; nt < 4; nt++) {
            const int n = n0 + wc*64 + nt*16 + l15;
            const float bias = bo[n];
#pragma unroll
            for (int r = 0; r < 4; r++)
                out[(mb + r)*1024 + n] = acc[mt][nt][r] + bias;
        }
    }
}

// ---------------------------------------------------------------------------
// Causal flash attention v10 = v7 with KVBLK 128 (half the serial segments):
//  * Same pairing (block owns q-tiles p and 15-p; uniform 34 tile-units) but
//    tiles are 128 kv wide -> 16-p iterations instead of 32-2p: HALF the
//    barriers + P-LDS drains per block, identical total MFMA (tile set covers
//    the same causal columns). Two 64-col halves processed per iteration.
//  * K fragments direct from global, 64-col-group register prefetch chain.
//  * V staged [d=64][kv=128+8pad], double-buffered, one barrier per tile.
//  * No setprio (R4 A/B: -1us on this lockstep structure, matches m190).
// ---------------------------------------------------------------------------
__global__ __launch_bounds__(512)
void flash_attn(const bf16* __restrict__ qd, const bf16* __restrict__ kd,
                const bf16* __restrict__ vtd, bf16* __restrict__ ctx)
{
    const int bh = blockIdx.x;            // 0..31 — same bh => same XCD
    const int p  = blockIdx.y;            // 0..7: this block owns q-tiles p and 15-p
    const int t = threadIdx.x;            // 0..511
    const int lane = t & 63, w = t >> 6;  // 8 waves
    const int l15 = lane & 15, quad = lane >> 4;
    const int side = w >> 2, wl = w & 3;  // side 0: tile p, side 1: tile 15-p
    const int q0 = (side ? (15 - p) : p) * 128;
    const int nT = 16 - p;                // 128-wide kv tiles (longer side)

    __shared__ bf16 Vs[2][64 * 136];      // [d][kv 128 + 8 pad]
    __shared__ bf16 Pl[8][16 * 72];

    const int mrow0 = q0 + wl * 16;
    const int mrow1 = q0 + 64 + wl * 16;

    v8s qf[2][2];
#pragma unroll
    for (int mt = 0; mt < 2; mt++) {
        const bf16* qb_ = qd + (bh*S_ + (mt ? mrow1 : mrow0) + l15) * HD_;
        qf[mt][0] = *(const v8s*)(qb_ + quad*8);
        qf[mt][1] = *(const v8s*)(qb_ + 32 + quad*8);
    }

    v4f o[2][4] = {};
    float ps[2][4] = {};

    // V staging: thread covers (d = t>>3, kv = (t&7)*8) and (.., kv+64)
    const int vrow = t >> 3, vcol = (t & 7) * 8;
    const bf16* vp = vtd + (bh*HD_ + vrow)*S_ + vcol;
    v8s pv0 = *(const v8s*)vp;
    v8s pv1 = *(const v8s*)(vp + 64);

    // K fragments direct from global, 64-group register prefetch chain
    const bf16* kbase = kd + (size_t)bh * S_ * HD_;
    v8s kf[4][2];
#pragma unroll
    for (int kt = 0; kt < 4; kt++) {
        const bf16* kp_ = kbase + (kt*16 + l15)*HD_ + quad*8;
        kf[kt][0] = *(const v8s*)kp_;
        kf[kt][1] = *(const v8s*)(kp_ + 32);
    }

    for (int it = 0; it < nT; ++it) {
        const int c0 = it * 128;
        bf16* Vb = &Vs[it & 1][0];
        *(v8s*)&Vb[vrow*136 + vcol]      = pv0;
        *(v8s*)&Vb[vrow*136 + 64 + vcol] = pv1;
        __syncthreads();
        vp += 128;
        pv0 = *(const v8s*)vp;            // prefetch next V tile (overrun stays in ws)
        pv1 = *(const v8s*)(vp + 64);

#pragma unroll
        for (int h = 0; h < 2; ++h) {
            const int ch = c0 + h * 64;
            const bool act  = (ch      <= mrow1 + 15);
            const bool nact = (ch + 64 <= mrow1 + 15);
            v8s nkf[4][2];
            if (nact) {                   // issue next 64-group K loads early
#pragma unroll
                for (int kt = 0; kt < 4; kt++) {
                    const bf16* kp_ = kbase + (ch + 64 + kt*16 + l15)*HD_ + quad*8;
                    nkf[kt][0] = *(const v8s*)kp_;
                    nkf[kt][1] = *(const v8s*)(kp_ + 32);
                }
            }

            if (act) {
                v8s vf[4][2];
#pragma unroll
                for (int dt = 0; dt < 4; dt++) {
                    vf[dt][0] = *(const v8s*)&Vb[(dt*16 + l15)*136 + h*64 + quad*8];
                    vf[dt][1] = *(const v8s*)&Vb[(dt*16 + l15)*136 + h*64 + 32 + quad*8];
                }

#pragma unroll
                for (int mt = 0; mt < 2; mt++) {
                    const int mr = mt ? mrow1 : mrow0;
                    if (ch > mr + 15) continue;
                    v4f sc[4] = {};
#pragma unroll
                    for (int kt = 0; kt < 4; kt++) {
                        sc[kt] = __builtin_amdgcn_mfma_f32_16x16x32_bf16(qf[mt][0], kf[kt][0], sc[kt], 0, 0, 0);
                        sc[kt] = __builtin_amdgcn_mfma_f32_16x16x32_bf16(qf[mt][1], kf[kt][1], sc[kt], 0, 0, 0);
                    }
                    const bool full = (ch + 63 <= mr);
#pragma unroll
                    for (int r = 0; r < 4; r++) {
                        const int qg = mr + quad*4 + r;
#pragma unroll
                        for (int kt = 0; kt < 4; kt++) {
                            float s = sc[kt][r];
                            if (!full) {
                                const int kg = ch + kt*16 + l15;
                                s = (kg <= qg) ? s : NEG_BIG;
                            }
                            const float pp = EXP2F(s);
                            sc[kt][r] = pp;
                            ps[mt][r] += pp;
                        }
                    }
                    bf16* pw = &Pl[w][0];
#pragma unroll
                    for (int kt = 0; kt < 4; kt++)
#pragma unroll
                        for (int r = 0; r < 4; r++)
                            pw[(quad*4 + r)*72 + kt*16 + l15] = __float2bfloat16(sc[kt][r]);
                    v8s pf0 = *(const v8s*)&pw[l15*72 + quad*8];
                    v8s pf1 = *(const v8s*)&pw[l15*72 + 32 + quad*8];
#pragma unroll
                    for (int dt = 0; dt < 4; dt++) {
                        o[mt][dt] = __builtin_amdgcn_mfma_f32_16x16x32_bf16(pf0, vf[dt][0], o[mt][dt], 0, 0, 0);
                        o[mt][dt] = __builtin_amdgcn_mfma_f32_16x16x32_bf16(pf1, vf[dt][1], o[mt][dt], 0, 0, 0);
                    }
                }
            }
            if (nact) {
#pragma unroll
                for (int kt = 0; kt < 4; kt++) { kf[kt][0] = nkf[kt][0]; kf[kt][1] = nkf[kt][1]; }
            }
        }
    }

    const int b_ = bh >> 4, hh = bh & 15;
#pragma unroll
    for (int mt = 0; mt < 2; mt++) {
        const int mr = mt ? mrow1 : mrow0;
#pragma unroll
        for (int r = 0; r < 4; r++) {
            float l = ps[mt][r];
#pragma unroll
            for (int off = 1; off < 16; off <<= 1) l += __shfl_xor(l, off);
            const float linv = 1.0f / l;
            const int qg = mr + quad*4 + r;
#pragma unroll
            for (int dt = 0; dt < 4; dt++)
                ctx[(b_*S_ + qg)*D_ + hh*HD_ + dt*16 + l15] = __float2bfloat16(o[mt][dt][r] * linv);
        }
    }
}

extern "C" void kernel_launch(void* const* d_in, const int* in_sizes, int n_in,
                              void* d_out, int out_size, void* d_ws, size_t ws_size,
                              hipStream_t stream) {
    const float* x  = (const float*)d_in[0];
    const float* Wq = (const float*)d_in[1];
    const float* Wk = (const float*)d_in[2];
    const float* Wv = (const float*)d_in[3];
    const float* Wo = (const float*)d_in[4];
    const float* bo = (const float*)d_in[5];
    float* out = (float*)d_out;

    const size_t SEG = (size_t)2 * H_ * S_ * HD_;      // 4 Mi bf16 elems = 8 MB
    bf16* qd  = (bf16*)d_ws;
    bf16* kd  = qd  + SEG;
    bf16* vtd = kd  + SEG;
    bf16* xc  = vtd + SEG;                             // x-bf16, later ctx
    bf16* wqb = xc + SEG;
    bf16* wkb = wqb + 1024 * 1024;
    bf16* wvb = wkb + 1024 * 1024;
    bf16* wob = wvb + 1024 * 1024;

    const size_t need_fast = (4 * SEG + 4 * 1024 * 1024) * sizeof(bf16);   // 40 MB

    if (ws_size >= need_fast) {
        cvt_bf16<<<dim3(2048, 5), 256, 0, stream>>>(x, Wq, Wk, Wv, Wo,
                                                    xc, wqb, wkb, wvb, wob);
        gemm_qkv_8p<<<dim3(16, 4, 3), 512, 0, stream>>>(xc, wqb, wkb, wvb, qd, kd, vtd);
        flash_attn<<<dim3(32, 8), 512, 0, stream>>>(qd, kd, vtd, xc);   // xc = ctx
        gemm_out_f<<<dim3(32, 8), 256, 0, stream>>>(xc, wob, bo, out);
    } else {
        gemm_qkv<<<dim3(32, 8, 3), 256, 0, stream>>>(x, Wq, Wk, Wv, qd, kd, vtd);
        flash_attn<<<dim3(32, 8), 512, 0, stream>>>(qd, kd, vtd, xc);
        gemm_out<<<dim3(32, 8), 256, 0, stream>>>(xc, Wo, bo, out);
    }
}

// Round 7
// 187.778 us; speedup vs baseline: 1.1877x; 1.0614x over previous
//
#include <hip/hip_runtime.h>
#include <hip/hip_bf16.h>

typedef __hip_bfloat16 bf16;
typedef short v8s __attribute__((ext_vector_type(8)));
typedef float v4f __attribute__((ext_vector_type(4)));
typedef float v16f __attribute__((ext_vector_type(16)));

#define S_ 2048
#define D_ 1024
#define H_ 16
#define HD_ 64

#define EXP2F(x) __builtin_amdgcn_exp2f(x)   /* v_exp_f32: 2^x on gfx950 */
#define NEG_BIG (-1.0e30f)
#define C2 0.1803368801111244f   /* (1/sqrt(64)) * log2(e), folded into Q */

#define GLDS16(g, l) __builtin_amdgcn_global_load_lds(                        \
    (const __attribute__((address_space(1))) unsigned int*)(g),               \
    (__attribute__((address_space(3))) unsigned int*)(l), 16, 0, 0)

#define CVT_PK(d, lo, hi) \
    asm("v_cvt_pk_bf16_f32 %0, %1, %2" : "=v"(d) : "v"(lo), "v"(hi))

/* exchanges high 32 lanes of a with low 32 lanes of b (gfx950) */
#define SWAPHALF(a, b) \
    asm("v_permlane32_swap_b32 %0, %1" : "+v"(a), "+v"(b))

#define MFMA32(a, b, c) __builtin_amdgcn_mfma_f32_32x32x16_bf16(a, b, c, 0, 0, 0)

static __device__ __forceinline__ unsigned short bf16_bits(bf16 h) {
    union { bf16 h; unsigned short u; } c; c.h = h; return c.u;
}

static __device__ __forceinline__ v8s pack_bf16x8(const float4 a, const float4 b) {
    union { v8s v; unsigned short u[8]; } r;
    r.u[0] = bf16_bits(__float2bfloat16(a.x));
    r.u[1] = bf16_bits(__float2bfloat16(a.y));
    r.u[2] = bf16_bits(__float2bfloat16(a.z));
    r.u[3] = bf16_bits(__float2bfloat16(a.w));
    r.u[4] = bf16_bits(__float2bfloat16(b.x));
    r.u[5] = bf16_bits(__float2bfloat16(b.y));
    r.u[6] = bf16_bits(__float2bfloat16(b.z));
    r.u[7] = bf16_bits(__float2bfloat16(b.w));
    return r.v;
}

// ---------------------------------------------------------------------------
// fp32 -> bf16 conversion pre-pass
// ---------------------------------------------------------------------------
__global__ __launch_bounds__(256)
void cvt_bf16(const float* __restrict__ x,  const float* __restrict__ wq,
              const float* __restrict__ wk, const float* __restrict__ wv,
              const float* __restrict__ wo,
              bf16* __restrict__ xb,  bf16* __restrict__ wqb,
              bf16* __restrict__ wkb, bf16* __restrict__ wvb,
              bf16* __restrict__ wob)
{
    const int seg = blockIdx.y;
    const float* src; bf16* dst; int n;
    switch (seg) {
        case 0: src = x;  dst = xb;  n = 4096 * 1024; break;
        case 1: src = wq; dst = wqb; n = 1024 * 1024; break;
        case 2: src = wk; dst = wkb; n = 1024 * 1024; break;
        case 3: src = wv; dst = wvb; n = 1024 * 1024; break;
        default:src = wo; dst = wob; n = 1024 * 1024; break;
    }
    const int idx = (blockIdx.x * 256 + threadIdx.x) * 8;
    if (idx >= n) return;
    *(v8s*)&dst[idx] = pack_bf16x8(*(const float4*)&src[idx],
                                   *(const float4*)&src[idx + 4]);
}

// ---------------------------------------------------------------------------
// QKV GEMM, 256x256 8-phase schedule (T3+T4+T5) + T2 XOR-swizzled LDS.
// (Verified round 4: T2 on the 8-phase structure gave ~-11us vs linear LDS.)
// ---------------------------------------------------------------------------
static __device__ __forceinline__ void stage_half(bf16* ldsbase, const bf16* gbase,
                                                  int w, int l) {
    const int r = l >> 3, c = ((l & 7) ^ r) * 8;  // T2 inverse-swizzled source
    GLDS16(gbase + (size_t)((2 * w + 0) * 8 + r) * 1024 + c, ldsbase + (2 * w + 0) * 512);
    GLDS16(gbase + (size_t)((2 * w + 1) * 8 + r) * 1024 + c, ldsbase + (2 * w + 1) * 512);
}

#define MF16(a, b, c) __builtin_amdgcn_mfma_f32_16x16x32_bf16(a, b, c, 0, 0, 0)

#define LDA(buf, mf0) { _Pragma("unroll") for (int m_ = 0; m_ < 4; ++m_) {          \
    af[m_][0] = *(const v8s*)&AsS[(buf)*16384 + abase + ((mf0) + m_)*1024 + sw0];   \
    af[m_][1] = *(const v8s*)&AsS[(buf)*16384 + abase + ((mf0) + m_)*1024 + sw1]; } }
#define LDB0(buf) { _Pragma("unroll") for (int n_ = 0; n_ < 2; ++n_) {              \
    b0f[n_][0] = *(const v8s*)&BsS[(buf)*16384 + bbase + n_*1024 + sw0];            \
    b0f[n_][1] = *(const v8s*)&BsS[(buf)*16384 + bbase + n_*1024 + sw1]; } }
#define LDB1(buf) { _Pragma("unroll") for (int n_ = 0; n_ < 2; ++n_) {              \
    b1f[n_][0] = *(const v8s*)&BsS[(buf)*16384 + bbase + (2 + n_)*1024 + sw0];      \
    b1f[n_][1] = *(const v8s*)&BsS[(buf)*16384 + bbase + (2 + n_)*1024 + sw1]; } }
#define MMQ(MH, NH, AF, BF) { _Pragma("unroll") for (int m_ = 0; m_ < 4; ++m_)      \
    _Pragma("unroll") for (int n_ = 0; n_ < 2; ++n_) {                              \
      acc[(MH)*4 + m_][(NH)*2 + n_] =                                               \
        MF16(AF[m_][0], BF[n_][0], acc[(MH)*4 + m_][(NH)*2 + n_]);                  \
      acc[(MH)*4 + m_][(NH)*2 + n_] =                                               \
        MF16(AF[m_][1], BF[n_][1], acc[(MH)*4 + m_][(NH)*2 + n_]); } }
#define BAR() __builtin_amdgcn_s_barrier()
#define VMC2() asm volatile("s_waitcnt vmcnt(2)" ::: "memory")
#define PRIO1() __builtin_amdgcn_s_setprio(1)
#define PRIO0() __builtin_amdgcn_s_setprio(0)

__global__ __launch_bounds__(512, 2)
void gemm_qkv_8p(const bf16* __restrict__ xb, const bf16* __restrict__ wqb,
                 const bf16* __restrict__ wkb, const bf16* __restrict__ wvb,
                 bf16* __restrict__ qd, bf16* __restrict__ kd, bf16* __restrict__ vtd)
{
    __shared__ bf16 AsS[2 * 16384];          // [buf][half 128][64]
    __shared__ bf16 BsS[2 * 16384];
    const int mode = blockIdx.z;
    const bf16* __restrict__ W = (mode == 0) ? wqb : (mode == 1) ? wkb : wvb;
    const int m0 = blockIdx.x * 256;
    const int n0 = blockIdx.y * 256;
    const int t = threadIdx.x;
    const int lane = t & 63, w = t >> 6;
    const int wr = w >> 2, wc = w & 3;       // 2M x 4N waves
    const int l15 = lane & 15, quad = lane >> 4;
    const int sw0 = (quad ^ (l15 & 7)) * 8;          // T2 swizzled col-slots
    const int sw1 = ((quad + 4) ^ (l15 & 7)) * 8;
    const int abase = wr * 8192 + l15 * 64;
    const int bbase = (wc >> 1) * 8192 + (wc & 1) * 4096 + l15 * 64;
    const bf16* Aap = xb + (size_t)m0 * 1024;
    const bf16* Bbp = W + (size_t)n0 * 1024;

    v4f acc[8][4] = {};
    v8s af[4][2], b0f[2][2], b1f[2][2];

    // prologue: tile0 (buf0, 4 halves) + tile1 A0 (buf1); keep tile1-A0 in flight
    stage_half(AsS,          Aap,          w, lane);
    stage_half(AsS + 8192,   Aap + 131072, w, lane);
    stage_half(BsS,          Bbp,          w, lane);
    stage_half(BsS + 8192,   Bbp + 131072, w, lane);
    stage_half(AsS + 16384,  Aap + 64,     w, lane);
    VMC2();
    BAR();

    for (int i = 0; i < 8; ++i) {
        const int kc = i * 128;
        // ph1: buf0 A-mh0 + B-nh0; stage tile(2i+1) A1 -> buf1
        LDA(0, 0); LDB0(0);
        stage_half(AsS + 16384 + 8192, Aap + 131072 + kc + 64, w, lane);
        BAR(); PRIO1(); MMQ(0, 0, af, b0f); PRIO0(); BAR();
        // ph2: buf0 B-nh1; stage tile(2i+1) B0 -> buf1
        LDB1(0);
        stage_half(BsS + 16384, Bbp + kc + 64, w, lane);
        BAR(); PRIO1(); MMQ(0, 1, af, b1f); PRIO0(); BAR();
        // ph3: buf0 A-mh1; stage tile(2i+1) B1 -> buf1
        LDA(0, 4);
        stage_half(BsS + 16384 + 8192, Bbp + 131072 + kc + 64, w, lane);
        BAR(); PRIO1(); MMQ(1, 1, af, b1f); PRIO0(); BAR();
        // ph4: stage tile(2i+2) A0 -> buf0; counted wait for tile(2i+1)
        stage_half(AsS, Aap + kc + 128, w, lane);
        VMC2();
        BAR(); PRIO1(); MMQ(1, 0, af, b0f); PRIO0(); BAR();
        // ph5: buf1 A-mh0 + B-nh0; stage tile(2i+2) A1 -> buf0
        LDA(1, 0); LDB0(1);
        stage_half(AsS + 8192, Aap + 131072 + kc + 128, w, lane);
        BAR(); PRIO1(); MMQ(0, 0, af, b0f); PRIO0(); BAR();
        // ph6: buf1 B-nh1; stage tile(2i+2) B0 -> buf0
        LDB1(1);
        stage_half(BsS, Bbp + kc + 128, w, lane);
        BAR(); PRIO1(); MMQ(0, 1, af, b1f); PRIO0(); BAR();
        // ph7: buf1 A-mh1; stage tile(2i+2) B1 -> buf0
        LDA(1, 4);
        stage_half(BsS + 8192, Bbp + 131072 + kc + 128, w, lane);
        BAR(); PRIO1(); MMQ(1, 1, af, b1f); PRIO0(); BAR();
        // ph8: stage tile(2i+3) A0 -> buf1; counted wait for tile(2i+2)
        stage_half(AsS + 16384, Aap + kc + 192, w, lane);
        VMC2();
        BAR(); PRIO1(); MMQ(1, 0, af, b0f); PRIO0(); BAR();
    }

    const float qscale = (mode == 0) ? C2 : 1.0f;
#pragma unroll
    for (int mf = 0; mf < 8; ++mf) {
        const int mb = m0 + wr * 128 + mf * 16 + quad * 4;
        const int b_ = mb >> 11, s = mb & 2047;
#pragma unroll
        for (int nf = 0; nf < 4; ++nf) {
            const int n = n0 + wc * 64 + nf * 16 + l15;
            const int h = n >> 6, d = n & 63;
            if (mode == 2) {
                unsigned int lo = (unsigned int)bf16_bits(__float2bfloat16(acc[mf][nf][0]))
                                | ((unsigned int)bf16_bits(__float2bfloat16(acc[mf][nf][1])) << 16);
                unsigned int hi = (unsigned int)bf16_bits(__float2bfloat16(acc[mf][nf][2]))
                                | ((unsigned int)bf16_bits(__float2bfloat16(acc[mf][nf][3])) << 16);
                uint2 pv; pv.x = lo; pv.y = hi;
                *(uint2*)&vtd[((b_ * H_ + h) * HD_ + d) * S_ + s] = pv;
            } else {
                bf16* __restrict__ dst = (mode == 0) ? qd : kd;
#pragma unroll
                for (int r = 0; r < 4; ++r)
                    dst[((b_ * H_ + h) * S_ + (s + r)) * HD_ + d] =
                        __float2bfloat16(acc[mf][nf][r] * qscale);
            }
        }
    }
}

// ---------------------------------------------------------------------------
// Output GEMM (m97-style 128x128): 256 blocks keeps all CUs busy at N=1024.
// ---------------------------------------------------------------------------
__global__ __launch_bounds__(256)
void gemm_out_f(const bf16* __restrict__ ctx, const bf16* __restrict__ wob,
                const float* __restrict__ bo, float* __restrict__ out)
{
    const int m0 = blockIdx.x * 128;
    const int n0 = blockIdx.y * 128;
    __shared__ bf16 As[128 * 32];
    __shared__ bf16 Bs[128 * 32];
    const int t    = threadIdx.x;
    const int lane = t & 63, w = t >> 6;
    const int wr = w >> 1, wc = w & 1;
    const int l15 = lane & 15, quad = lane >> 4;
    const int r16 = lane >> 2, c8 = (lane & 3) * 8;
    v4f acc[4][4] = {};

    const bf16* ga = &ctx[(m0 + w*16 + r16) * 1024 + c8];
    const bf16* gb = &wob[(n0 + w*16 + r16) * 1024 + c8];
    bf16* la0 = &As[w * 16 * 32];
    bf16* la1 = &As[(64 + w * 16) * 32];
    bf16* lb0 = &Bs[w * 16 * 32];
    bf16* lb1 = &Bs[(64 + w * 16) * 32];

    for (int k0 = 0; k0 < 1024; k0 += 32) {
        __syncthreads();
        GLDS16(ga + k0,             la0);
        GLDS16(ga + k0 + 64 * 1024, la1);
        GLDS16(gb + k0,             lb0);
        GLDS16(gb + k0 + 64 * 1024, lb1);
        __syncthreads();
        v8s a[4], b[4];
#pragma unroll
        for (int mt = 0; mt < 4; mt++) a[mt] = *(const v8s*)&As[(wr*64 + mt*16 + l15)*32 + quad*8];
#pragma unroll
        for (int nt = 0; nt < 4; nt++) b[nt] = *(const v8s*)&Bs[(wc*64 + nt*16 + l15)*32 + quad*8];
#pragma unroll
        for (int mt = 0; mt < 4; mt++)
#pragma unroll
            for (int nt = 0; nt < 4; nt++)
                acc[mt][nt] = __builtin_amdgcn_mfma_f32_16x16x32_bf16(a[mt], b[nt], acc[mt][nt], 0, 0, 0);
    }

#pragma unroll
    for (int mt = 0; mt < 4; mt++) {
        const int mb = m0 + wr*64 + mt*16 + quad*4;
#pragma unroll
        for (int nt = 0; nt < 4; nt++) {
            const int n = n0 + wc*64 + nt*16 + l15;
            const float bias = bo[n];
#pragma unroll
            for (int r = 0; r < 4; r++)
                out[(mb + r)*1024 + n] = acc[mt][nt][r] + bias;
        }
    }
}

// ---------------------------------------------------------------------------
// FALLBACK GEMMs (fp32 inputs, cvt fused in staging)
// ---------------------------------------------------------------------------
__global__ __launch_bounds__(256)
void gemm_qkv(const float* __restrict__ x, const float* __restrict__ Wq,
              const float* __restrict__ Wk, const float* __restrict__ Wv,
              bf16* __restrict__ qd, bf16* __restrict__ kd, bf16* __restrict__ vtd)
{
    const int mode = blockIdx.z;
    const float* __restrict__ W = (mode == 0) ? Wq : (mode == 1) ? Wk : Wv;
    const int m0 = blockIdx.x * 128;
    const int n0 = blockIdx.y * 128;
    __shared__ bf16 As[128 * 40];
    __shared__ bf16 Bs[128 * 40];
    const int t    = threadIdx.x;
    const int lane = t & 63, w = t >> 6;
    const int wr = w >> 1, wc = w & 1;
    const int l15 = lane & 15, quad = lane >> 4;
    const int srow = t >> 2, scol = (t & 3) * 8;
    v4f acc[4][4] = {};

    for (int k0 = 0; k0 < 1024; k0 += 32) {
        __syncthreads();
        {
            const float* pa = &x[(m0 + srow) * 1024 + k0 + scol];
            *(v8s*)&As[srow*40 + scol] = pack_bf16x8(*(const float4*)pa, *(const float4*)(pa + 4));
            const float* pa2 = pa + 64 * 1024;
            *(v8s*)&As[(srow+64)*40 + scol] = pack_bf16x8(*(const float4*)pa2, *(const float4*)(pa2 + 4));
            const float* pb = &W[(n0 + srow) * 1024 + k0 + scol];
            *(v8s*)&Bs[srow*40 + scol] = pack_bf16x8(*(const float4*)pb, *(const float4*)(pb + 4));
            const float* pb2 = pb + 64 * 1024;
            *(v8s*)&Bs[(srow+64)*40 + scol] = pack_bf16x8(*(const float4*)pb2, *(const float4*)(pb2 + 4));
        }
        __syncthreads();
        v8s a[4], b[4];
#pragma unroll
        for (int mt = 0; mt < 4; mt++) a[mt] = *(const v8s*)&As[(wr*64 + mt*16 + l15)*40 + quad*8];
#pragma unroll
        for (int nt = 0; nt < 4; nt++) b[nt] = *(const v8s*)&Bs[(wc*64 + nt*16 + l15)*40 + quad*8];
#pragma unroll
        for (int mt = 0; mt < 4; mt++)
#pragma unroll
            for (int nt = 0; nt < 4; nt++)
                acc[mt][nt] = __builtin_amdgcn_mfma_f32_16x16x32_bf16(a[mt], b[nt], acc[mt][nt], 0, 0, 0);
    }

    const float qscale = (mode == 0) ? C2 : 1.0f;
#pragma unroll
    for (int mt = 0; mt < 4; mt++) {
        const int mb = m0 + wr*64 + mt*16 + quad*4;
        const int b_ = mb >> 11, s = mb & 2047;
#pragma unroll
        for (int nt = 0; nt < 4; nt++) {
            const int n = n0 + wc*64 + nt*16 + l15;
            const int h = n >> 6, d = n & 63;
            if (mode == 2) {
                unsigned int lo = (unsigned int)bf16_bits(__float2bfloat16(acc[mt][nt][0]))
                                | ((unsigned int)bf16_bits(__float2bfloat16(acc[mt][nt][1])) << 16);
                unsigned int hi = (unsigned int)bf16_bits(__float2bfloat16(acc[mt][nt][2]))
                                | ((unsigned int)bf16_bits(__float2bfloat16(acc[mt][nt][3])) << 16);
                uint2 pv; pv.x = lo; pv.y = hi;
                *(uint2*)&vtd[((b_*H_ + h)*HD_ + d)*S_ + s] = pv;
            } else {
                bf16* __restrict__ dst = (mode == 0) ? qd : kd;
#pragma unroll
                for (int r = 0; r < 4; r++)
                    dst[((b_*H_ + h)*S_ + (s + r))*HD_ + d] = __float2bfloat16(acc[mt][nt][r] * qscale);
            }
        }
    }
}

__global__ __launch_bounds__(256)
void gemm_out(const bf16* __restrict__ ctx, const float* __restrict__ Wo,
              const float* __restrict__ bo, float* __restrict__ out)
{
    const int m0 = blockIdx.x * 128;
    const int n0 = blockIdx.y * 128;
    __shared__ bf16 As[128 * 40];
    __shared__ bf16 Bs[128 * 40];
    const int t    = threadIdx.x;
    const int lane = t & 63, w = t >> 6;
    const int wr = w >> 1, wc = w & 1;
    const int l15 = lane & 15, quad = lane >> 4;
    const int srow = t >> 2, scol = (t & 3) * 8;
    v4f acc[4][4] = {};

    for (int k0 = 0; k0 < 1024; k0 += 32) {
        __syncthreads();
        {
            *(v8s*)&As[srow*40 + scol]      = *(const v8s*)&ctx[(m0+srow)*1024 + k0 + scol];
            *(v8s*)&As[(srow+64)*40 + scol] = *(const v8s*)&ctx[(m0+srow+64)*1024 + k0 + scol];
            const float* pb = &Wo[(n0 + srow) * 1024 + k0 + scol];
            *(v8s*)&Bs[srow*40 + scol] = pack_bf16x8(*(const float4*)pb, *(const float4*)(pb + 4));
            const float* pb2 = pb + 64 * 1024;
            *(v8s*)&Bs[(srow+64)*40 + scol] = pack_bf16x8(*(const float4*)pb2, *(const float4*)(pb2 + 4));
        }
        __syncthreads();
        v8s a[4], b[4];
#pragma unroll
        for (int mt = 0; mt < 4; mt++) a[mt] = *(const v8s*)&As[(wr*64 + mt*16 + l15)*40 + quad*8];
#pragma unroll
        for (int nt = 0; nt < 4; nt++) b[nt] = *(const v8s*)&Bs[(wc*64 + nt*16 + l15)*40 + quad*8];
#pragma unroll
        for (int mt = 0; mt < 4; mt++)
#pragma unroll
            for (int nt = 0; nt < 4; nt++)
                acc[mt][nt] = __builtin_amdgcn_mfma_f32_16x16x32_bf16(a[mt], b[nt], acc[mt][nt], 0, 0, 0);
    }

#pragma unroll
    for (int mt = 0; mt < 4; mt++) {
        const int mb = m0 + wr*64 + mt*16 + quad*4;
#pragma unroll
        for (int nt = 0; nt < 4; nt++) {
            const int n = n0 + wc*64 + nt*16 + l15;
            const float bias = bo[n];
#pragma unroll
            for (int r = 0; r < 4; r++)
                out[(mb + r)*1024 + n] = acc[mt][nt][r] + bias;
        }
    }
}

// ---------------------------------------------------------------------------
// Causal flash attention v11 = v10 shell + v9's verified 32x32 swapped-QK +
// in-register softmax (T12):
//  * 8 waves = 2 sides x 4 waves; each wave owns 32 q-rows (side = 128).
//    Same uniform pairing (p, 15-p), KVBLK=128, V double-buffer, 1 barrier.
//  * QK^T computed swapped (mfma_32x32x16(K, Q)): lane holds P column q=l31;
//    P->bf16 A-fragments rebuilt with 8x v_cvt_pk_bf16_f32 + 4x
//    v_permlane32_swap_b32 per 32-col group (verified v9 round 2) ->
//    NO P LDS round-trip, no mid-iteration lgkm drain.
//  * K direct from global with consume-then-prefetch chain (v10 pattern).
//  * V fragments from LDS as 32x32 B-operands (b128, row = l31 / l31+32).
// ---------------------------------------------------------------------------
#define SOFTMAX_PV(sa, ks0, vA0, vA1, vB0, vB1)                                \
    {                                                                          \
        const bool full_ = ((ks0) + 31 <= q0w);                                \
        if (full_) {                                                           \
            _Pragma("unroll")                                                  \
            for (int r = 0; r < 16; r++) {                                     \
                const float p = EXP2F(sa[r]); sa[r] = p;                       \
                if (r & 1) ps1 += p; else ps0 += p;                            \
            }                                                                  \
        } else {                                                               \
            const int kb_ = (ks0) + 4 * hi - q0w - l31;                        \
            _Pragma("unroll")                                                  \
            for (int r = 0; r < 16; r++) {                                     \
                const int kl_ = (r & 3) + 8 * (r >> 2);                        \
                const float p = EXP2F((kb_ + kl_ <= 0) ? sa[r] : NEG_BIG);     \
                sa[r] = p;                                                     \
                if (r & 1) ps1 += p; else ps0 += p;                            \
            }                                                                  \
        }                                                                      \
        unsigned u0, u1, u2, u3, u4, u5, u6, u7;                               \
        CVT_PK(u0, sa[0],  sa[1]);  CVT_PK(u1, sa[2],  sa[3]);                 \
        CVT_PK(u2, sa[4],  sa[5]);  CVT_PK(u3, sa[6],  sa[7]);                 \
        CVT_PK(u4, sa[8],  sa[9]);  CVT_PK(u5, sa[10], sa[11]);                \
        CVT_PK(u6, sa[12], sa[13]); CVT_PK(u7, sa[14], sa[15]);                \
        SWAPHALF(u0, u2); SWAPHALF(u1, u3);                                    \
        SWAPHALF(u4, u6); SWAPHALF(u5, u7);                                    \
        union { v8s v; unsigned w[4]; } pa0_, pa1_;                            \
        pa0_.w[0] = u0; pa0_.w[1] = u1; pa0_.w[2] = u2; pa0_.w[3] = u3;        \
        pa1_.w[0] = u4; pa1_.w[1] = u5; pa1_.w[2] = u6; pa1_.w[3] = u7;        \
        o0 = MFMA32(pa0_.v, vA0, o0);                                          \
        o1 = MFMA32(pa0_.v, vB0, o1);                                          \
        o0 = MFMA32(pa1_.v, vA1, o0);                                          \
        o1 = MFMA32(pa1_.v, vB1, o1);                                          \
    }

__global__ __launch_bounds__(512)
void flash_attn(const bf16* __restrict__ qd, const bf16* __restrict__ kd,
                const bf16* __restrict__ vtd, bf16* __restrict__ ctx)
{
    const int bh = blockIdx.x;            // 0..31 — same bh => same XCD
    const int p  = blockIdx.y;            // 0..7: block owns q-tiles p and 15-p
    const int t = threadIdx.x;            // 0..511
    const int lane = t & 63, w = t >> 6;  // 8 waves
    const int l31 = lane & 31, hi = lane >> 5;
    const int side = w >> 2, wl = w & 3;  // side 0: tile p, side 1: tile 15-p
    const int q0w = (side ? (15 - p) : p) * 128 + wl * 32;   // wave's 32 q-rows
    const int nT = 16 - p;                // 128-wide kv tiles (longer side)

    __shared__ bf16 Vs[2][64 * 136];      // [d][kv 128 + 8 pad]

    // Q B-frags (col=q=l31, k-elem=d=hi*8+j+16*c), resident whole kernel
    const bf16* qp = qd + ((size_t)bh * S_ + q0w + l31) * HD_ + hi * 8;
    const v8s qf0 = *(const v8s*)(qp);
    const v8s qf1 = *(const v8s*)(qp + 16);
    const v8s qf2 = *(const v8s*)(qp + 32);
    const v8s qf3 = *(const v8s*)(qp + 48);

    v16f o0 = {}, o1 = {};                // d = l31 / l31+32; q via regs
    float ps0 = 0.f, ps1 = 0.f;

    // V staging: thread covers (d = t>>3, kv = (t&7)*8) and (.., kv+64)
    const int vrow = t >> 3, vcol = (t & 7) * 8;
    const bf16* vp = vtd + ((size_t)bh * HD_ + vrow) * S_ + vcol;
    v8s pv0 = *(const v8s*)vp;
    v8s pv1 = *(const v8s*)(vp + 64);

    // K A-frags (row=k=l31 (+32 for B-group), k-elem=d), group 0
    const bf16* kq = kd + ((size_t)bh * S_ + l31) * HD_ + hi * 8;
    v8s kA0 = *(const v8s*)(kq);
    v8s kA1 = *(const v8s*)(kq + 16);
    v8s kA2 = *(const v8s*)(kq + 32);
    v8s kA3 = *(const v8s*)(kq + 48);
    v8s kB0 = *(const v8s*)(kq + 32 * HD_);
    v8s kB1 = *(const v8s*)(kq + 32 * HD_ + 16);
    v8s kB2 = *(const v8s*)(kq + 32 * HD_ + 32);
    v8s kB3 = *(const v8s*)(kq + 32 * HD_ + 48);

    for (int it = 0; it < nT; ++it) {
        const int c0 = it * 128;
        bf16* Vb = &Vs[it & 1][0];
        *(v8s*)&Vb[vrow*136 + vcol]      = pv0;
        *(v8s*)&Vb[vrow*136 + 64 + vcol] = pv1;
        __syncthreads();
        vp += 128;
        pv0 = *(const v8s*)vp;            // prefetch next V tile (overrun stays in ws)
        pv1 = *(const v8s*)(vp + 64);

#pragma unroll
        for (int h = 0; h < 2; ++h) {
            const int ch = c0 + h * 64;
            const bool actA = (ch      <= q0w + 31);
            const bool actB = (ch + 32 <= q0w + 31);
            const bool nact = (ch + 64 <= q0w + 31);

            v16f sa0 = {}, sa1 = {};
            if (actA) {
                sa0 = MFMA32(kA0, qf0, sa0);
                sa0 = MFMA32(kA1, qf1, sa0);
                sa0 = MFMA32(kA2, qf2, sa0);
                sa0 = MFMA32(kA3, qf3, sa0);
            }
            if (actB) {
                sa1 = MFMA32(kB0, qf0, sa1);
                sa1 = MFMA32(kB1, qf1, sa1);
                sa1 = MFMA32(kB2, qf2, sa1);
                sa1 = MFMA32(kB3, qf3, sa1);
            }

            // K consumed -> prefetch next 64-group into the same registers
            if (nact) {
                const bf16* kn = kq + (size_t)(ch + 64) * HD_;
                kA0 = *(const v8s*)(kn);
                kA1 = *(const v8s*)(kn + 16);
                kA2 = *(const v8s*)(kn + 32);
                kA3 = *(const v8s*)(kn + 48);
                kB0 = *(const v8s*)(kn + 32 * HD_);
                kB1 = *(const v8s*)(kn + 32 * HD_ + 16);
                kB2 = *(const v8s*)(kn + 32 * HD_ + 32);
                kB3 = *(const v8s*)(kn + 32 * HD_ + 48);
            }

            if (actA) {
                const int kb = h * 64;
                const v8s vA0 = *(const v8s*)&Vb[ l31      *136 + kb      + hi*8];
                const v8s vA1 = *(const v8s*)&Vb[ l31      *136 + kb + 16 + hi*8];
                const v8s vB0 = *(const v8s*)&Vb[(l31 + 32)*136 + kb      + hi*8];
                const v8s vB1 = *(const v8s*)&Vb[(l31 + 32)*136 + kb + 16 + hi*8];
                SOFTMAX_PV(sa0, ch, vA0, vA1, vB0, vB1);
            }
            if (actB) {
                const int kb = h * 64 + 32;
                const v8s vA2 = *(const v8s*)&Vb[ l31      *136 + kb      + hi*8];
                const v8s vA3 = *(const v8s*)&Vb[ l31      *136 + kb + 16 + hi*8];
                const v8s vB2 = *(const v8s*)&Vb[(l31 + 32)*136 + kb      + hi*8];
                const v8s vB3 = *(const v8s*)&Vb[(l31 + 32)*136 + kb + 16 + hi*8];
                SOFTMAX_PV(sa1, ch + 32, vA2, vA3, vB2, vB3);
            }
        }
    }

    // denominator for q=l31: this lane's half + the other hi half
    const float ps = ps0 + ps1;
    const float tot = ps + __shfl_xor(ps, 32);
    const int b_ = bh >> 4, hh = bh & 15;
    bf16* cb = ctx + ((size_t)b_ * S_ + q0w) * D_ + hh * HD_ + l31;
#pragma unroll
    for (int r = 0; r < 16; r++) {
        const int qr = (r & 3) + 8 * (r >> 2) + 4 * hi;
        const float linv = 1.0f / __shfl(tot, qr);
        cb[(size_t)qr * D_]      = __float2bfloat16(o0[r] * linv);
        cb[(size_t)qr * D_ + 32] = __float2bfloat16(o1[r] * linv);
    }
}

extern "C" void kernel_launch(void* const* d_in, const int* in_sizes, int n_in,
                              void* d_out, int out_size, void* d_ws, size_t ws_size,
                              hipStream_t stream) {
    const float* x  = (const float*)d_in[0];
    const float* Wq = (const float*)d_in[1];
    const float* Wk = (const float*)d_in[2];
    const float* Wv = (const float*)d_in[3];
    const float* Wo = (const float*)d_in[4];
    const float* bo = (const float*)d_in[5];
    float* out = (float*)d_out;

    const size_t SEG = (size_t)2 * H_ * S_ * HD_;      // 4 Mi bf16 elems = 8 MB
    bf16* qd  = (bf16*)d_ws;
    bf16* kd  = qd  + SEG;
    bf16* vtd = kd  + SEG;
    bf16* xc  = vtd + SEG;                             // x-bf16, later ctx
    bf16* wqb = xc + SEG;
    bf16* wkb = wqb + 1024 * 1024;
    bf16* wvb = wkb + 1024 * 1024;
    bf16* wob = wvb + 1024 * 1024;

    const size_t need_fast = (4 * SEG + 4 * 1024 * 1024) * sizeof(bf16);   // 40 MB

    if (ws_size >= need_fast) {
        cvt_bf16<<<dim3(2048, 5), 256, 0, stream>>>(x, Wq, Wk, Wv, Wo,
                                                    xc, wqb, wkb, wvb, wob);
        gemm_qkv_8p<<<dim3(16, 4, 3), 512, 0, stream>>>(xc, wqb, wkb, wvb, qd, kd, vtd);
        flash_attn<<<dim3(32, 8), 512, 0, stream>>>(qd, kd, vtd, xc);   // xc = ctx
        gemm_out_f<<<dim3(32, 8), 256, 0, stream>>>(xc, wob, bo, out);
    } else {
        gemm_qkv<<<dim3(32, 8, 3), 256, 0, stream>>>(x, Wq, Wk, Wv, qd, kd, vtd);
        flash_attn<<<dim3(32, 8), 512, 0, stream>>>(qd, kd, vtd, xc);
        gemm_out<<<dim3(32, 8), 256, 0, stream>>>(xc, Wo, bo, out);
    }
}